// Round 1
// baseline (755.117 us; speedup 1.0000x reference)
//
#include <hip/hip_runtime.h>

// GIN forward, MI355X. fp32 baseline, CSR-sorted aggregation, BN fused into GEMMs.

#define NN 50000
#define EE 800000
#define FDIM 128
#define HDIM 256
#define CDIM 40
#define BN_EPS 1e-5f

// ---------------- CSR build ----------------
__global__ void k_hist(const int* __restrict__ ei, int* __restrict__ deg) {
  int e = blockIdx.x * 256 + threadIdx.x;
  if (e < EE) atomicAdd(&deg[ei[EE + e]], 1);
}

__global__ void k_scan_blocks(const int* __restrict__ in, int* __restrict__ partial,
                              int* __restrict__ bsums, int n) {
  __shared__ int s[256];
  int i = blockIdx.x * 256 + threadIdx.x;
  s[threadIdx.x] = (i < n) ? in[i] : 0;
  __syncthreads();
  for (int d = 1; d < 256; d <<= 1) {
    int t = (threadIdx.x >= d) ? s[threadIdx.x - d] : 0;
    __syncthreads();
    s[threadIdx.x] += t;
    __syncthreads();
  }
  if (i < n) partial[i] = s[threadIdx.x];
  if (threadIdx.x == 255) bsums[blockIdx.x] = s[255];
}

__global__ void k_scan_sums(int* __restrict__ bs, int nb) {
  __shared__ int s[256];
  s[threadIdx.x] = (threadIdx.x < nb) ? bs[threadIdx.x] : 0;
  __syncthreads();
  for (int d = 1; d < 256; d <<= 1) {
    int t = (threadIdx.x >= d) ? s[threadIdx.x - d] : 0;
    __syncthreads();
    s[threadIdx.x] += t;
    __syncthreads();
  }
  int ex = (threadIdx.x == 0) ? 0 : s[threadIdx.x - 1];
  if (threadIdx.x < nb) bs[threadIdx.x] = ex;
}

__global__ void k_scan_add(const int* __restrict__ partial, const int* __restrict__ bs,
                           int* __restrict__ rowstart, int n) {
  int i = blockIdx.x * 256 + threadIdx.x;
  if (i < n) rowstart[i + 1] = partial[i] + bs[blockIdx.x];
  if (i == 0) rowstart[0] = 0;
}

__global__ void k_copy_i32(const int* __restrict__ a, int* __restrict__ b, int n) {
  int i = blockIdx.x * 256 + threadIdx.x;
  if (i < n) b[i] = a[i];
}

__global__ void k_scatter(const int* __restrict__ ei, int* __restrict__ cursor,
                          int* __restrict__ sorted_src) {
  int e = blockIdx.x * 256 + threadIdx.x;
  if (e < EE) {
    int dst = ei[EE + e];
    int p = atomicAdd(&cursor[dst], 1);
    sorted_src[p] = ei[e];
  }
}

// ---------------- aggregation: out[i] = (1+eps)*x[i] + sum_{e: dst=i} x[src] ----------------
template <int FEAT>
__global__ __launch_bounds__(256)
void k_aggregate(const float* __restrict__ x, const int* __restrict__ rowstart,
                 const int* __restrict__ sorted_src, const float* __restrict__ epsp,
                 float* __restrict__ out) {
  int node = blockIdx.x * 4 + (threadIdx.x >> 6);
  if (node >= NN) return;
  int lane = threadIdx.x & 63;
  float e1 = 1.0f + epsp[0];
  int s = rowstart[node], t = rowstart[node + 1];
  if constexpr (FEAT == 128) {
    float2 acc = *(const float2*)&x[(size_t)node * 128 + lane * 2];
    acc.x *= e1; acc.y *= e1;
    for (int p = s; p < t; ++p) {
      int src = sorted_src[p];
      float2 v = *(const float2*)&x[(size_t)src * 128 + lane * 2];
      acc.x += v.x; acc.y += v.y;
    }
    *(float2*)&out[(size_t)node * 128 + lane * 2] = acc;
  } else {
    float4 acc = *(const float4*)&x[(size_t)node * 256 + lane * 4];
    acc.x *= e1; acc.y *= e1; acc.z *= e1; acc.w *= e1;
    for (int p = s; p < t; ++p) {
      int src = sorted_src[p];
      float4 v = *(const float4*)&x[(size_t)src * 256 + lane * 4];
      acc.x += v.x; acc.y += v.y; acc.z += v.z; acc.w += v.w;
    }
    *(float4*)&out[(size_t)node * 256 + lane * 4] = acc;
  }
}

// ---------------- main GEMM: C[NN,256] = opA(A[NN,K]) @ B[K,256] + bias ----------------
// opA(v, k) = relu(v*ta[k]+tc[k]) if TRANSFORM (BN+ReLU of previous layer, fused on load)
// optional relu on output; optional per-column sum/sumsq accumulation (for next BN)
#define BM 128
#define BNT 128
#define BK 32
#define LDA 132
#define LDB 132

template <int K, bool TRANSFORM, bool RELU_OUT, bool COLSUMS>
__global__ __launch_bounds__(256)
void k_gemm(const float* __restrict__ A, const float* __restrict__ B,
            const float* __restrict__ bias,
            const float* __restrict__ ta, const float* __restrict__ tc,
            float* __restrict__ C,
            float* __restrict__ csum, float* __restrict__ csq) {
  __shared__ float As[BK][LDA];
  __shared__ float Bs[BK][LDB];
  int tid = threadIdx.x;
  int tx = tid & 15, ty = tid >> 4;
  int r0 = blockIdx.x * BM;
  int n0 = blockIdx.y * BNT;
  float acc[8][8] = {};

  for (int k0 = 0; k0 < K; k0 += BK) {
    // A tile: BM x BK, store transposed As[k][m]
#pragma unroll
    for (int i = 0; i < 4; ++i) {
      int idx = tid + i * 256;        // 0..1023
      int row = idx >> 3;             // 0..127
      int c4 = (idx & 7) * 4;         // 0..28
      int gr = r0 + row;
      float4 v = make_float4(0.f, 0.f, 0.f, 0.f);
      if (gr < NN) {
        v = *(const float4*)&A[(size_t)gr * K + k0 + c4];
        if constexpr (TRANSFORM) {
          v.x = fmaxf(fmaf(v.x, ta[k0 + c4 + 0], tc[k0 + c4 + 0]), 0.f);
          v.y = fmaxf(fmaf(v.y, ta[k0 + c4 + 1], tc[k0 + c4 + 1]), 0.f);
          v.z = fmaxf(fmaf(v.z, ta[k0 + c4 + 2], tc[k0 + c4 + 2]), 0.f);
          v.w = fmaxf(fmaf(v.w, ta[k0 + c4 + 3], tc[k0 + c4 + 3]), 0.f);
        }
      }
      As[c4 + 0][row] = v.x;
      As[c4 + 1][row] = v.y;
      As[c4 + 2][row] = v.z;
      As[c4 + 3][row] = v.w;
    }
    // B tile: BK x BNT
#pragma unroll
    for (int i = 0; i < 4; ++i) {
      int idx = tid + i * 256;
      int row = idx >> 5;             // 0..31
      int c4 = (idx & 31) * 4;        // 0..124
      float4 v = *(const float4*)&B[(size_t)(k0 + row) * HDIM + n0 + c4];
      *(float4*)&Bs[row][c4] = v;
    }
    __syncthreads();
#pragma unroll
    for (int k = 0; k < BK; ++k) {
      float4 a0 = *(const float4*)&As[k][ty * 8];
      float4 a1 = *(const float4*)&As[k][ty * 8 + 4];
      float4 b0 = *(const float4*)&Bs[k][tx * 8];
      float4 b1 = *(const float4*)&Bs[k][tx * 8 + 4];
      float a[8] = {a0.x, a0.y, a0.z, a0.w, a1.x, a1.y, a1.z, a1.w};
      float b[8] = {b0.x, b0.y, b0.z, b0.w, b1.x, b1.y, b1.z, b1.w};
#pragma unroll
      for (int i = 0; i < 8; ++i)
#pragma unroll
        for (int j = 0; j < 8; ++j) acc[i][j] = fmaf(a[i], b[j], acc[i][j]);
    }
    __syncthreads();
  }

  float bsv[8];
#pragma unroll
  for (int j = 0; j < 8; ++j) bsv[j] = bias[n0 + tx * 8 + j];
  float colS[8] = {}, colQ[8] = {};
#pragma unroll
  for (int i = 0; i < 8; ++i) {
    int gr = r0 + ty * 8 + i;
    if (gr < NN) {
      float vr[8];
#pragma unroll
      for (int j = 0; j < 8; ++j) {
        float v = acc[i][j] + bsv[j];
        if constexpr (RELU_OUT) v = fmaxf(v, 0.f);
        vr[j] = v;
        if constexpr (COLSUMS) { colS[j] += v; colQ[j] += v * v; }
      }
      *(float4*)&C[(size_t)gr * HDIM + n0 + tx * 8] = make_float4(vr[0], vr[1], vr[2], vr[3]);
      *(float4*)&C[(size_t)gr * HDIM + n0 + tx * 8 + 4] = make_float4(vr[4], vr[5], vr[6], vr[7]);
    }
  }
  if constexpr (COLSUMS) {
    __syncthreads();
    float* redS = &As[0][0];  // 16*128 floats, fits in As
    float* redQ = &Bs[0][0];
#pragma unroll
    for (int j = 0; j < 8; ++j) {
      redS[ty * 128 + tx * 8 + j] = colS[j];
      redQ[ty * 128 + tx * 8 + j] = colQ[j];
    }
    __syncthreads();
    if (tid < 128) {
      float s = 0.f, q = 0.f;
#pragma unroll
      for (int t = 0; t < 16; ++t) { s += redS[t * 128 + tid]; q += redQ[t * 128 + tid]; }
      atomicAdd(&csum[n0 + tid], s);
      atomicAdd(&csq[n0 + tid], q);
    }
  }
}

// ---------------- BN finalize: a = g*rsqrt(var+eps), c = be - m*a ----------------
__global__ void k_bn_fin(const float* __restrict__ sum, const float* __restrict__ sq,
                         const float* __restrict__ g, const float* __restrict__ be,
                         float* __restrict__ a, float* __restrict__ c) {
  int t = threadIdx.x;
  float m = sum[t] * (1.0f / NN);
  float var = sq[t] * (1.0f / NN) - m * m;
  float s = g[t] * rsqrtf(var + BN_EPS);
  a[t] = s;
  c[t] = be[t] - m * s;
}

// ---------------- final GEMM: out[NN,40] = relu(z*ta+tc) @ Wf + bf ----------------
__global__ __launch_bounds__(256)
void k_gemm_final(const float* __restrict__ A, const float* __restrict__ B,
                  const float* __restrict__ bias, const float* __restrict__ ta,
                  const float* __restrict__ tc, float* __restrict__ C) {
  __shared__ float As[64][65];   // [k][r]
  __shared__ float Bs[64][CDIM];
  int tid = threadIdx.x;
  int r = tid & 63, q = tid >> 6;  // q in 0..3, 10 cols each
  int r0 = blockIdx.x * 64;
  float acc[10] = {};
  for (int k0 = 0; k0 < HDIM; k0 += 64) {
#pragma unroll
    for (int i = 0; i < 4; ++i) {
      int idx = tid + i * 256;      // 0..1023
      int row = idx >> 4;           // 0..63
      int c4 = (idx & 15) * 4;      // 0..60
      int gr = r0 + row;
      float4 v = make_float4(0.f, 0.f, 0.f, 0.f);
      if (gr < NN) {
        v = *(const float4*)&A[(size_t)gr * HDIM + k0 + c4];
        v.x = fmaxf(fmaf(v.x, ta[k0 + c4 + 0], tc[k0 + c4 + 0]), 0.f);
        v.y = fmaxf(fmaf(v.y, ta[k0 + c4 + 1], tc[k0 + c4 + 1]), 0.f);
        v.z = fmaxf(fmaf(v.z, ta[k0 + c4 + 2], tc[k0 + c4 + 2]), 0.f);
        v.w = fmaxf(fmaf(v.w, ta[k0 + c4 + 3], tc[k0 + c4 + 3]), 0.f);
      }
      As[c4 + 0][row] = v.x;
      As[c4 + 1][row] = v.y;
      As[c4 + 2][row] = v.z;
      As[c4 + 3][row] = v.w;
    }
#pragma unroll
    for (int i = 0; i < 10; ++i) {
      int idx = tid + i * 256;      // 0..2559
      int row = idx / CDIM;
      int col = idx % CDIM;
      Bs[row][col] = B[(size_t)(k0 + row) * CDIM + col];
    }
    __syncthreads();
#pragma unroll
    for (int k = 0; k < 64; ++k) {
      float a = As[k][r];
#pragma unroll
      for (int j = 0; j < 10; ++j) acc[j] = fmaf(a, Bs[k][q * 10 + j], acc[j]);
    }
    __syncthreads();
  }
  int gr = r0 + r;
  if (gr < NN) {
#pragma unroll
    for (int j = 0; j < 10; ++j) C[(size_t)gr * CDIM + q * 10 + j] = acc[j] + bias[q * 10 + j];
  }
}

// ---------------- launch ----------------
extern "C" void kernel_launch(void* const* d_in, const int* in_sizes, int n_in,
                              void* d_out, int out_size, void* d_ws, size_t ws_size,
                              hipStream_t stream) {
  const float* x   = (const float*)d_in[0];
  const int*   ei  = (const int*)d_in[1];
  const float* eps1= (const float*)d_in[2];
  const float* W1  = (const float*)d_in[3];
  const float* b1  = (const float*)d_in[4];
  const float* g1  = (const float*)d_in[5];
  const float* be1 = (const float*)d_in[6];
  const float* W2  = (const float*)d_in[7];
  const float* b2  = (const float*)d_in[8];
  const float* eps2= (const float*)d_in[9];
  const float* W3  = (const float*)d_in[10];
  const float* b3  = (const float*)d_in[11];
  const float* g2  = (const float*)d_in[12];
  const float* be2 = (const float*)d_in[13];
  const float* W4  = (const float*)d_in[14];
  const float* b4  = (const float*)d_in[15];
  const float* g3  = (const float*)d_in[16];
  const float* be3 = (const float*)d_in[17];
  const float* Wf  = (const float*)d_in[18];
  const float* bf  = (const float*)d_in[19];
  float* out = (float*)d_out;

  // workspace layout
  float* B0 = (float*)d_ws;                       // [NN,256]
  float* B1 = B0 + (size_t)NN * HDIM;             // [NN,256]
  float* B2 = B1 + (size_t)NN * HDIM;             // [NN,256]
  float* stats = B2 + (size_t)NN * HDIM;          // 12*256: s1,q1,a1,c1, s2,q2,a2,c2, s3,q3,a3,c3
  int* deg      = (int*)(stats + 12 * HDIM);      // NN
  int* rowstart = deg + NN;                       // NN+1
  int* cursor   = rowstart + NN + 1;              // NN
  int* sorted   = cursor + NN;                    // EE
  int* partial  = sorted + EE;                    // NN
  int* bsums    = partial + NN;                   // 256

  hipMemsetAsync(deg, 0, NN * sizeof(int), stream);
  hipMemsetAsync(stats, 0, 12 * HDIM * sizeof(float), stream);

  const int nbE = (EE + 255) / 256;
  const int nbN = (NN + 255) / 256;   // 196

  k_hist<<<nbE, 256, 0, stream>>>(ei, deg);
  k_scan_blocks<<<nbN, 256, 0, stream>>>(deg, partial, bsums, NN);
  k_scan_sums<<<1, 256, 0, stream>>>(bsums, nbN);
  k_scan_add<<<nbN, 256, 0, stream>>>(partial, bsums, rowstart, NN);
  k_copy_i32<<<nbN, 256, 0, stream>>>(rowstart, cursor, NN);
  k_scatter<<<nbE, 256, 0, stream>>>(ei, cursor, sorted);

  dim3 gG((NN + BM - 1) / BM, HDIM / BNT);

  // conv1
  k_aggregate<128><<<(NN + 3) / 4, 256, 0, stream>>>(x, rowstart, sorted, eps1, B0);
  k_gemm<128, false, false, true><<<gG, 256, 0, stream>>>(
      B0, W1, b1, nullptr, nullptr, B1, stats + 0, stats + 256);
  k_bn_fin<<<1, 256, 0, stream>>>(stats + 0, stats + 256, g1, be1, stats + 2 * 256, stats + 3 * 256);
  k_gemm<256, true, true, false><<<gG, 256, 0, stream>>>(
      B1, W2, b2, stats + 2 * 256, stats + 3 * 256, B2, nullptr, nullptr);

  // conv2
  k_aggregate<256><<<(NN + 3) / 4, 256, 0, stream>>>(B2, rowstart, sorted, eps2, B0);
  k_gemm<256, false, false, true><<<gG, 256, 0, stream>>>(
      B0, W3, b3, nullptr, nullptr, B1, stats + 4 * 256, stats + 5 * 256);
  k_bn_fin<<<1, 256, 0, stream>>>(stats + 4 * 256, stats + 5 * 256, g2, be2, stats + 6 * 256, stats + 7 * 256);
  k_gemm<256, true, false, true><<<gG, 256, 0, stream>>>(
      B1, W4, b4, stats + 6 * 256, stats + 7 * 256, B0, stats + 8 * 256, stats + 9 * 256);
  k_bn_fin<<<1, 256, 0, stream>>>(stats + 8 * 256, stats + 9 * 256, g3, be3, stats + 10 * 256, stats + 11 * 256);

  // bn2+relu fused into final GEMM
  k_gemm_final<<<(NN + 63) / 64, 256, 0, stream>>>(
      B0, Wf, bf, stats + 10 * 256, stats + 11 * 256, out);
}

// Round 2
// 503.927 us; speedup vs baseline: 1.4985x; 1.4985x over previous
//
#include <hip/hip_runtime.h>

// GIN forward, MI355X. bf16 MFMA GEMMs + bf16 CSR aggregation, BN fused.

#define NN 50000
#define EE 800000
#define FDIM 128
#define HDIM 256
#define CDIM 40
#define BN_EPS 1e-5f

typedef unsigned short u16;
typedef unsigned int u32;
typedef __attribute__((ext_vector_type(8))) short short8;
typedef __attribute__((ext_vector_type(4))) float f32x4;

__device__ __forceinline__ float bflo(u32 u) { return __uint_as_float(u << 16); }
__device__ __forceinline__ float bfhi(u32 u) { return __uint_as_float(u & 0xFFFF0000u); }
__device__ __forceinline__ u16 f2bf(float f) {
  u32 u = __float_as_uint(f);
  return (u16)((u + 0x7FFFu + ((u >> 16) & 1u)) >> 16);
}
__device__ __forceinline__ u32 pack2(float a, float b) {
  return (u32)f2bf(a) | ((u32)f2bf(b) << 16);
}

// ---------------- CSR build ----------------
__global__ void k_hist(const int* __restrict__ ei, int* __restrict__ deg) {
  int e = blockIdx.x * 256 + threadIdx.x;
  if (e < EE) atomicAdd(&deg[ei[EE + e]], 1);
}

__global__ void k_scan_blocks(const int* __restrict__ in, int* __restrict__ partial,
                              int* __restrict__ bsums, int n) {
  __shared__ int s[256];
  int i = blockIdx.x * 256 + threadIdx.x;
  s[threadIdx.x] = (i < n) ? in[i] : 0;
  __syncthreads();
  for (int d = 1; d < 256; d <<= 1) {
    int t = (threadIdx.x >= d) ? s[threadIdx.x - d] : 0;
    __syncthreads();
    s[threadIdx.x] += t;
    __syncthreads();
  }
  if (i < n) partial[i] = s[threadIdx.x];
  if (threadIdx.x == 255) bsums[blockIdx.x] = s[255];
}

__global__ void k_scan_sums(int* __restrict__ bs, int nb) {
  __shared__ int s[256];
  s[threadIdx.x] = (threadIdx.x < nb) ? bs[threadIdx.x] : 0;
  __syncthreads();
  for (int d = 1; d < 256; d <<= 1) {
    int t = (threadIdx.x >= d) ? s[threadIdx.x - d] : 0;
    __syncthreads();
    s[threadIdx.x] += t;
    __syncthreads();
  }
  int ex = (threadIdx.x == 0) ? 0 : s[threadIdx.x - 1];
  if (threadIdx.x < nb) bs[threadIdx.x] = ex;
}

__global__ void k_scan_add(const int* __restrict__ partial, const int* __restrict__ bs,
                           int* __restrict__ rowstart, int n) {
  int i = blockIdx.x * 256 + threadIdx.x;
  if (i < n) rowstart[i + 1] = partial[i] + bs[blockIdx.x];
  if (i == 0) rowstart[0] = 0;
}

__global__ void k_copy_i32(const int* __restrict__ a, int* __restrict__ b, int n) {
  int i = blockIdx.x * 256 + threadIdx.x;
  if (i < n) b[i] = a[i];
}

__global__ void k_scatter(const int* __restrict__ ei, int* __restrict__ cursor,
                          int* __restrict__ sorted_src) {
  int e = blockIdx.x * 256 + threadIdx.x;
  if (e < EE) {
    int dst = ei[EE + e];
    int p = atomicAdd(&cursor[dst], 1);
    sorted_src[p] = ei[e];
  }
}

// ---------------- conversions ----------------
__global__ void k_cvt_x(const float* __restrict__ x, u16* __restrict__ xb) {
  int i = blockIdx.x * 256 + threadIdx.x;  // handles 4 elems
  size_t base = (size_t)i * 4;
  if (base < (size_t)NN * FDIM) {
    float4 v = *(const float4*)&x[base];
    u32 lo = pack2(v.x, v.y), hi = pack2(v.z, v.w);
    *(uint2*)&xb[base] = make_uint2(lo, hi);
  }
}

// W [K,256] fp32 -> Wt [256,K] bf16 (transpose)
__global__ void k_cvt_wt(const float* __restrict__ W, u16* __restrict__ Wt, int K) {
  int i = blockIdx.x * 256 + threadIdx.x;
  int k = i >> 8, n = i & 255;
  if (k < K) Wt[(size_t)n * K + k] = f2bf(W[i]);
}

// ---------------- aggregation (bf16 in/out, f32 accumulate) ----------------
template <int FEAT>
__global__ __launch_bounds__(256)
void k_agg(const u16* __restrict__ x, const int* __restrict__ rowstart,
           const int* __restrict__ sorted_src, const float* __restrict__ epsp,
           u16* __restrict__ out) {
  int node = blockIdx.x * 4 + (threadIdx.x >> 6);
  if (node >= NN) return;
  int lane = threadIdx.x & 63;
  float e1 = 1.0f + epsp[0];
  int s = rowstart[node], t = rowstart[node + 1];
  if constexpr (FEAT == 128) {
    u32 u = *(const u32*)&x[(size_t)node * 128 + lane * 2];
    float a0 = bflo(u) * e1, a1 = bfhi(u) * e1;
    int p = s;
    for (; p + 1 < t; p += 2) {
      int s0 = sorted_src[p], s1 = sorted_src[p + 1];
      u32 u0 = *(const u32*)&x[(size_t)s0 * 128 + lane * 2];
      u32 u1 = *(const u32*)&x[(size_t)s1 * 128 + lane * 2];
      a0 += bflo(u0) + bflo(u1);
      a1 += bfhi(u0) + bfhi(u1);
    }
    if (p < t) {
      u32 u0 = *(const u32*)&x[(size_t)sorted_src[p] * 128 + lane * 2];
      a0 += bflo(u0); a1 += bfhi(u0);
    }
    *(u32*)&out[(size_t)node * 128 + lane * 2] = pack2(a0, a1);
  } else {
    uint2 u = *(const uint2*)&x[(size_t)node * 256 + lane * 4];
    float a0 = bflo(u.x) * e1, a1 = bfhi(u.x) * e1;
    float a2 = bflo(u.y) * e1, a3 = bfhi(u.y) * e1;
    int p = s;
    for (; p + 1 < t; p += 2) {
      int s0 = sorted_src[p], s1 = sorted_src[p + 1];
      uint2 u0 = *(const uint2*)&x[(size_t)s0 * 256 + lane * 4];
      uint2 u1 = *(const uint2*)&x[(size_t)s1 * 256 + lane * 4];
      a0 += bflo(u0.x) + bflo(u1.x);
      a1 += bfhi(u0.x) + bfhi(u1.x);
      a2 += bflo(u0.y) + bflo(u1.y);
      a3 += bfhi(u0.y) + bfhi(u1.y);
    }
    if (p < t) {
      uint2 u0 = *(const uint2*)&x[(size_t)sorted_src[p] * 256 + lane * 4];
      a0 += bflo(u0.x); a1 += bfhi(u0.x);
      a2 += bflo(u0.y); a3 += bfhi(u0.y);
    }
    *(uint2*)&out[(size_t)node * 256 + lane * 4] = make_uint2(pack2(a0, a1), pack2(a2, a3));
  }
}

// ---------------- MFMA GEMM: C[M,256] = opA(A[M,K]) @ Bt[256,K]^T + bias ----------------
// opA = relu(v*ta[k]+tc[k]) if TRANSFORM. Optional relu-out, optional colsums.
// 128x128 tile, BK=64, 4 waves 2x2, each 64x64 via 4x4 16x16x32 frags.
// LDS: [row][64] bf16 rows (128B), 16B chunks XOR-swizzled by (row&7) -> 2-way reads.
template <int K, bool TRANSFORM, bool RELU_OUT, bool COLSUMS>
__global__ __launch_bounds__(256)
void k_gemm(const u16* __restrict__ A, const u16* __restrict__ Bt,
            const float* __restrict__ bias, const float* __restrict__ ta,
            const float* __restrict__ tc, u16* __restrict__ C,
            float* __restrict__ csum, float* __restrict__ csq) {
  __shared__ u16 As[128 * 64];
  __shared__ u16 Bs[128 * 64];
  const int tid = threadIdx.x;
  const int lane = tid & 63;
  const int w = tid >> 6;
  const int wm = w >> 1, wn = w & 1;
  const int lr = lane & 15, lq = lane >> 4;
  const int r0 = blockIdx.x * 128;
  const int n0 = blockIdx.y * 128;

  f32x4 acc[4][4];
#pragma unroll
  for (int i = 0; i < 4; ++i)
#pragma unroll
    for (int j = 0; j < 4; ++j) acc[i][j] = (f32x4){0.f, 0.f, 0.f, 0.f};

  for (int k0 = 0; k0 < K; k0 += 64) {
    // stage A: 128 rows x 8 chunks(16B)
#pragma unroll
    for (int it = 0; it < 4; ++it) {
      int idx = tid + it * 256;
      int m = idx >> 3, q = idx & 7;
      int gm = r0 + m;
      short8 v = (short8)0;
      if (gm < NN) {
        v = *(const short8*)&A[(size_t)gm * K + k0 + q * 8];
        if constexpr (TRANSFORM) {
#pragma unroll
          for (int j = 0; j < 8; ++j) {
            float f = __uint_as_float(((u32)(u16)v[j]) << 16);
            float t = fmaxf(fmaf(f, ta[k0 + q * 8 + j], tc[k0 + q * 8 + j]), 0.f);
            v[j] = (short)f2bf(t);
          }
        }
      }
      ((short8*)As)[m * 8 + (q ^ (m & 7))] = v;
    }
    // stage Bt rows n0..n0+127
#pragma unroll
    for (int it = 0; it < 4; ++it) {
      int idx = tid + it * 256;
      int m = idx >> 3, q = idx & 7;
      short8 v = *(const short8*)&Bt[(size_t)(n0 + m) * K + k0 + q * 8];
      ((short8*)Bs)[m * 8 + (q ^ (m & 7))] = v;
    }
    __syncthreads();
#pragma unroll
    for (int ks = 0; ks < 2; ++ks) {
      short8 af[4], bfr[4];
#pragma unroll
      for (int mi = 0; mi < 4; ++mi) {
        int row = wm * 64 + mi * 16 + lr;
        int ch = (ks * 4 + lq) ^ (row & 7);
        af[mi] = ((const short8*)As)[row * 8 + ch];
      }
#pragma unroll
      for (int ni = 0; ni < 4; ++ni) {
        int row = wn * 64 + ni * 16 + lr;
        int ch = (ks * 4 + lq) ^ (row & 7);
        bfr[ni] = ((const short8*)Bs)[row * 8 + ch];
      }
#pragma unroll
      for (int mi = 0; mi < 4; ++mi)
#pragma unroll
        for (int ni = 0; ni < 4; ++ni)
          acc[mi][ni] = __builtin_amdgcn_mfma_f32_16x16x32_bf16(af[mi], bfr[ni], acc[mi][ni], 0, 0, 0);
    }
    __syncthreads();
  }

  // epilogue: C/D layout col=lane&15, row=lq*4+reg
  float colS[4] = {}, colQ[4] = {};
#pragma unroll
  for (int ni = 0; ni < 4; ++ni) {
    int col = n0 + wn * 64 + ni * 16 + lr;
    float bv = bias[col];
#pragma unroll
    for (int mi = 0; mi < 4; ++mi) {
      int rbase = r0 + wm * 64 + mi * 16 + lq * 4;
#pragma unroll
      for (int j = 0; j < 4; ++j) {
        int row = rbase + j;
        if (row < NN) {
          float v = acc[mi][ni][j] + bv;
          if constexpr (RELU_OUT) v = fmaxf(v, 0.f);
          C[(size_t)row * HDIM + col] = f2bf(v);
          if constexpr (COLSUMS) { colS[ni] += v; colQ[ni] += v * v; }
        }
      }
    }
  }
  if constexpr (COLSUMS) {
#pragma unroll
    for (int ni = 0; ni < 4; ++ni) {
      float s = colS[ni], q = colQ[ni];
      s += __shfl_xor(s, 16); s += __shfl_xor(s, 32);
      q += __shfl_xor(q, 16); q += __shfl_xor(q, 32);
      if (lq == 0) {
        int col = n0 + wn * 64 + ni * 16 + lr;
        atomicAdd(&csum[col], s);
        atomicAdd(&csq[col], q);
      }
    }
  }
}

// ---------------- BN finalize ----------------
__global__ void k_bn_fin(const float* __restrict__ sum, const float* __restrict__ sq,
                         const float* __restrict__ g, const float* __restrict__ be,
                         float* __restrict__ a, float* __restrict__ c) {
  int t = threadIdx.x;
  float m = sum[t] * (1.0f / NN);
  float var = sq[t] * (1.0f / NN) - m * m;
  float s = g[t] * rsqrtf(var + BN_EPS);
  a[t] = s;
  c[t] = be[t] - m * s;
}

// ---------------- final GEMM: out[NN,40] = relu(z*ta+tc) @ Wf + bf (fp32 vector) ----------------
__global__ __launch_bounds__(256)
void k_gemm_final(const u16* __restrict__ A, const float* __restrict__ B,
                  const float* __restrict__ bias, const float* __restrict__ ta,
                  const float* __restrict__ tc, float* __restrict__ C) {
  __shared__ float As[64][65];
  __shared__ float Bs[64][CDIM];
  int tid = threadIdx.x;
  int r = tid & 63, q = tid >> 6;
  int r0 = blockIdx.x * 64;
  float acc[10] = {};
  for (int k0 = 0; k0 < HDIM; k0 += 64) {
#pragma unroll
    for (int i = 0; i < 4; ++i) {
      int idx = tid + i * 256;
      int row = idx >> 4;
      int c4 = (idx & 15) * 4;
      int gr = r0 + row;
      float v0 = 0.f, v1 = 0.f, v2 = 0.f, v3 = 0.f;
      if (gr < NN) {
        uint2 u = *(const uint2*)&A[(size_t)gr * HDIM + k0 + c4];
        v0 = fmaxf(fmaf(bflo(u.x), ta[k0 + c4 + 0], tc[k0 + c4 + 0]), 0.f);
        v1 = fmaxf(fmaf(bfhi(u.x), ta[k0 + c4 + 1], tc[k0 + c4 + 1]), 0.f);
        v2 = fmaxf(fmaf(bflo(u.y), ta[k0 + c4 + 2], tc[k0 + c4 + 2]), 0.f);
        v3 = fmaxf(fmaf(bfhi(u.y), ta[k0 + c4 + 3], tc[k0 + c4 + 3]), 0.f);
      }
      As[c4 + 0][row] = v0;
      As[c4 + 1][row] = v1;
      As[c4 + 2][row] = v2;
      As[c4 + 3][row] = v3;
    }
#pragma unroll
    for (int i = 0; i < 10; ++i) {
      int idx = tid + i * 256;
      int row = idx / CDIM;
      int col = idx % CDIM;
      Bs[row][col] = B[(size_t)(k0 + row) * CDIM + col];
    }
    __syncthreads();
#pragma unroll
    for (int k = 0; k < 64; ++k) {
      float a = As[k][r];
#pragma unroll
      for (int j = 0; j < 10; ++j) acc[j] = fmaf(a, Bs[k][q * 10 + j], acc[j]);
    }
    __syncthreads();
  }
  int gr = r0 + r;
  if (gr < NN) {
#pragma unroll
    for (int j = 0; j < 10; ++j) C[(size_t)gr * CDIM + q * 10 + j] = acc[j] + bias[q * 10 + j];
  }
}

// ---------------- launch ----------------
extern "C" void kernel_launch(void* const* d_in, const int* in_sizes, int n_in,
                              void* d_out, int out_size, void* d_ws, size_t ws_size,
                              hipStream_t stream) {
  const float* x   = (const float*)d_in[0];
  const int*   ei  = (const int*)d_in[1];
  const float* eps1= (const float*)d_in[2];
  const float* W1  = (const float*)d_in[3];
  const float* b1  = (const float*)d_in[4];
  const float* g1  = (const float*)d_in[5];
  const float* be1 = (const float*)d_in[6];
  const float* W2  = (const float*)d_in[7];
  const float* b2  = (const float*)d_in[8];
  const float* eps2= (const float*)d_in[9];
  const float* W3  = (const float*)d_in[10];
  const float* b3  = (const float*)d_in[11];
  const float* g2  = (const float*)d_in[12];
  const float* be2 = (const float*)d_in[13];
  const float* W4  = (const float*)d_in[14];
  const float* b4  = (const float*)d_in[15];
  const float* g3  = (const float*)d_in[16];
  const float* be3 = (const float*)d_in[17];
  const float* Wf  = (const float*)d_in[18];
  const float* bf  = (const float*)d_in[19];
  float* out = (float*)d_out;

  // workspace carve-up (256B aligned slabs)
  char* p = (char*)d_ws;
  auto alloc = [&](size_t bytes) -> char* {
    char* r = p;
    p += (bytes + 255) & ~(size_t)255;
    return r;
  };
  float* stats   = (float*)alloc(12 * 256 * sizeof(float));
  int* deg       = (int*)alloc(NN * sizeof(int));
  int* rowstart  = (int*)alloc((NN + 16) * sizeof(int));
  int* cursor    = (int*)alloc(NN * sizeof(int));
  int* sorted    = (int*)alloc(EE * sizeof(int));
  int* partial   = (int*)alloc(NN * sizeof(int));
  int* bsums     = (int*)alloc(1024 * sizeof(int));
  u16* W1t       = (u16*)alloc(256 * 128 * sizeof(u16));
  u16* W2t       = (u16*)alloc(256 * 256 * sizeof(u16));
  u16* W3t       = (u16*)alloc(256 * 256 * sizeof(u16));
  u16* W4t       = (u16*)alloc(256 * 256 * sizeof(u16));
  u16* xb        = (u16*)alloc((size_t)NN * 128 * sizeof(u16));
  u16* A1        = (u16*)alloc((size_t)NN * 128 * sizeof(u16));
  u16* z1        = (u16*)alloc((size_t)NN * 256 * sizeof(u16));
  u16* h1        = (u16*)alloc((size_t)NN * 256 * sizeof(u16));
  u16* A2        = (u16*)alloc((size_t)NN * 256 * sizeof(u16));
  u16* z2 = z1;  // z1 dead after gemm2
  u16* z3 = h1;  // h1 dead after agg2

  hipMemsetAsync(deg, 0, NN * sizeof(int), stream);
  hipMemsetAsync(stats, 0, 12 * 256 * sizeof(float), stream);

  const int nbE = (EE + 255) / 256;
  const int nbN = (NN + 255) / 256;

  k_hist<<<nbE, 256, 0, stream>>>(ei, deg);
  k_scan_blocks<<<nbN, 256, 0, stream>>>(deg, partial, bsums, NN);
  k_scan_sums<<<1, 256, 0, stream>>>(bsums, nbN);
  k_scan_add<<<nbN, 256, 0, stream>>>(partial, bsums, rowstart, NN);
  k_copy_i32<<<nbN, 256, 0, stream>>>(rowstart, cursor, NN);
  k_scatter<<<nbE, 256, 0, stream>>>(ei, cursor, sorted);

  k_cvt_x<<<(NN * FDIM / 4 + 255) / 256, 256, 0, stream>>>(x, xb);
  k_cvt_wt<<<128, 256, 0, stream>>>(W1, W1t, 128);
  k_cvt_wt<<<256, 256, 0, stream>>>(W2, W2t, 256);
  k_cvt_wt<<<256, 256, 0, stream>>>(W3, W3t, 256);
  k_cvt_wt<<<256, 256, 0, stream>>>(W4, W4t, 256);

  dim3 gG((NN + 127) / 128, 2);

  // conv1
  k_agg<128><<<(NN + 3) / 4, 256, 0, stream>>>(xb, rowstart, sorted, eps1, A1);
  k_gemm<128, false, false, true><<<gG, 256, 0, stream>>>(
      A1, W1t, b1, nullptr, nullptr, z1, stats + 0, stats + 256);
  k_bn_fin<<<1, 256, 0, stream>>>(stats + 0, stats + 256, g1, be1,
                                  stats + 2 * 256, stats + 3 * 256);
  k_gemm<256, true, true, false><<<gG, 256, 0, stream>>>(
      z1, W2t, b2, stats + 2 * 256, stats + 3 * 256, h1, nullptr, nullptr);

  // conv2
  k_agg<256><<<(NN + 3) / 4, 256, 0, stream>>>(h1, rowstart, sorted, eps2, A2);
  k_gemm<256, false, false, true><<<gG, 256, 0, stream>>>(
      A2, W3t, b3, nullptr, nullptr, z2, stats + 4 * 256, stats + 5 * 256);
  k_bn_fin<<<1, 256, 0, stream>>>(stats + 4 * 256, stats + 5 * 256, g2, be2,
                                  stats + 6 * 256, stats + 7 * 256);
  k_gemm<256, true, false, true><<<gG, 256, 0, stream>>>(
      z2, W4t, b4, stats + 6 * 256, stats + 7 * 256, z3, stats + 8 * 256, stats + 9 * 256);
  k_bn_fin<<<1, 256, 0, stream>>>(stats + 8 * 256, stats + 9 * 256, g3, be3,
                                  stats + 10 * 256, stats + 11 * 256);

  // bn2+relu fused into final GEMM
  k_gemm_final<<<(NN + 63) / 64, 256, 0, stream>>>(
      z3, Wf, bf, stats + 10 * 256, stats + 11 * 256, out);
}

// Round 3
// 492.755 us; speedup vs baseline: 1.5324x; 1.0227x over previous
//
#include <hip/hip_runtime.h>
#include <hip/hip_bf16.h>

// GIN forward, MI355X. bf16 MFMA GEMMs (2-phase prefetch) + unrolled bf16 CSR aggregation.

#define NN 50000
#define EE 800000
#define FDIM 128
#define HDIM 256
#define CDIM 40
#define BN_EPS 1e-5f

typedef unsigned short u16;
typedef unsigned int u32;
typedef __attribute__((ext_vector_type(8))) short short8;
typedef __attribute__((ext_vector_type(4))) float f32x4;

__device__ __forceinline__ float bflo(u32 u) { return __uint_as_float(u << 16); }
__device__ __forceinline__ float bfhi(u32 u) { return __uint_as_float(u & 0xFFFF0000u); }
__device__ __forceinline__ u16 f2bf(float f) {
  __hip_bfloat16 h = __float2bfloat16(f);   // RNE; compiler fuses pairs into v_cvt_pk_bf16_f32
  return *(u16*)&h;
}
__device__ __forceinline__ u32 pack2(float a, float b) {
  return (u32)f2bf(a) | ((u32)f2bf(b) << 16);
}

// ---------------- CSR build ----------------
__global__ void k_hist(const int* __restrict__ ei, int* __restrict__ deg) {
  int e = blockIdx.x * 256 + threadIdx.x;
  if (e < EE) atomicAdd(&deg[ei[EE + e]], 1);
}

__global__ void k_scan_blocks(const int* __restrict__ in, int* __restrict__ partial,
                              int* __restrict__ bsums, int n) {
  __shared__ int s[256];
  int i = blockIdx.x * 256 + threadIdx.x;
  s[threadIdx.x] = (i < n) ? in[i] : 0;
  __syncthreads();
  for (int d = 1; d < 256; d <<= 1) {
    int t = (threadIdx.x >= d) ? s[threadIdx.x - d] : 0;
    __syncthreads();
    s[threadIdx.x] += t;
    __syncthreads();
  }
  if (i < n) partial[i] = s[threadIdx.x];
  if (threadIdx.x == 255) bsums[blockIdx.x] = s[255];
}

__global__ void k_scan_sums(int* __restrict__ bs, int nb) {
  __shared__ int s[256];
  s[threadIdx.x] = (threadIdx.x < nb) ? bs[threadIdx.x] : 0;
  __syncthreads();
  for (int d = 1; d < 256; d <<= 1) {
    int t = (threadIdx.x >= d) ? s[threadIdx.x - d] : 0;
    __syncthreads();
    s[threadIdx.x] += t;
    __syncthreads();
  }
  int ex = (threadIdx.x == 0) ? 0 : s[threadIdx.x - 1];
  if (threadIdx.x < nb) bs[threadIdx.x] = ex;
}

__global__ void k_scan_add(const int* __restrict__ partial, const int* __restrict__ bs,
                           int* __restrict__ rowstart, int n) {
  int i = blockIdx.x * 256 + threadIdx.x;
  if (i < n) rowstart[i + 1] = partial[i] + bs[blockIdx.x];
  if (i == 0) rowstart[0] = 0;
}

__global__ void k_copy_i32(const int* __restrict__ a, int* __restrict__ b, int n) {
  int i = blockIdx.x * 256 + threadIdx.x;
  if (i < n) b[i] = a[i];
}

__global__ void k_scatter(const int* __restrict__ ei, int* __restrict__ cursor,
                          int* __restrict__ sorted_src) {
  int e = blockIdx.x * 256 + threadIdx.x;
  if (e < EE) {
    int dst = ei[EE + e];
    int p = atomicAdd(&cursor[dst], 1);
    sorted_src[p] = ei[e];
  }
}

// ---------------- conversions ----------------
__global__ void k_cvt_x(const float* __restrict__ x, u16* __restrict__ xb) {
  int i = blockIdx.x * 256 + threadIdx.x;
  size_t base = (size_t)i * 4;
  if (base < (size_t)NN * FDIM) {
    float4 v = *(const float4*)&x[base];
    u32 lo = pack2(v.x, v.y), hi = pack2(v.z, v.w);
    *(uint2*)&xb[base] = make_uint2(lo, hi);
  }
}

// W [K,256] fp32 -> Wt [256,K] bf16 (transpose)
__global__ void k_cvt_wt(const float* __restrict__ W, u16* __restrict__ Wt, int K) {
  int i = blockIdx.x * 256 + threadIdx.x;
  int k = i >> 8, n = i & 255;
  if (k < K) Wt[(size_t)n * K + k] = f2bf(W[i]);
}

// ---------------- aggregation (bf16 in/out, f32 accumulate, 4-deep MLP) ----------------
template <int FEAT>
__global__ __launch_bounds__(256)
void k_agg(const u16* __restrict__ x, const int* __restrict__ rowstart,
           const int* __restrict__ sorted_src, const float* __restrict__ epsp,
           u16* __restrict__ out) {
  int node = blockIdx.x * 4 + (threadIdx.x >> 6);
  if (node >= NN) return;
  int lane = threadIdx.x & 63;
  float e1 = 1.0f + epsp[0];
  int s = rowstart[node], t = rowstart[node + 1];
  if constexpr (FEAT == 128) {
    const u32* xp = (const u32*)x;      // row = 64 u32
    u32 u = xp[(size_t)node * 64 + lane];
    float a0 = bflo(u) * e1, a1 = bfhi(u) * e1;
    int p = s;
    for (; p + 3 < t; p += 4) {
      int s0 = sorted_src[p], s1 = sorted_src[p + 1];
      int s2 = sorted_src[p + 2], s3 = sorted_src[p + 3];
      u32 u0 = xp[(size_t)s0 * 64 + lane];
      u32 u1 = xp[(size_t)s1 * 64 + lane];
      u32 u2 = xp[(size_t)s2 * 64 + lane];
      u32 u3 = xp[(size_t)s3 * 64 + lane];
      a0 += (bflo(u0) + bflo(u1)) + (bflo(u2) + bflo(u3));
      a1 += (bfhi(u0) + bfhi(u1)) + (bfhi(u2) + bfhi(u3));
    }
    for (; p < t; ++p) {
      u32 u0 = xp[(size_t)sorted_src[p] * 64 + lane];
      a0 += bflo(u0); a1 += bfhi(u0);
    }
    ((u32*)out)[(size_t)node * 64 + lane] = pack2(a0, a1);
  } else {
    const uint2* xp = (const uint2*)x;  // row = 64 uint2
    uint2 u = xp[(size_t)node * 64 + lane];
    float a0 = bflo(u.x) * e1, a1 = bfhi(u.x) * e1;
    float a2 = bflo(u.y) * e1, a3 = bfhi(u.y) * e1;
    int p = s;
    for (; p + 3 < t; p += 4) {
      int s0 = sorted_src[p], s1 = sorted_src[p + 1];
      int s2 = sorted_src[p + 2], s3 = sorted_src[p + 3];
      uint2 u0 = xp[(size_t)s0 * 64 + lane];
      uint2 u1 = xp[(size_t)s1 * 64 + lane];
      uint2 u2 = xp[(size_t)s2 * 64 + lane];
      uint2 u3 = xp[(size_t)s3 * 64 + lane];
      a0 += (bflo(u0.x) + bflo(u1.x)) + (bflo(u2.x) + bflo(u3.x));
      a1 += (bfhi(u0.x) + bfhi(u1.x)) + (bfhi(u2.x) + bfhi(u3.x));
      a2 += (bflo(u0.y) + bflo(u1.y)) + (bflo(u2.y) + bflo(u3.y));
      a3 += (bfhi(u0.y) + bfhi(u1.y)) + (bfhi(u2.y) + bfhi(u3.y));
    }
    for (; p < t; ++p) {
      uint2 u0 = xp[(size_t)sorted_src[p] * 64 + lane];
      a0 += bflo(u0.x); a1 += bfhi(u0.x);
      a2 += bflo(u0.y); a3 += bfhi(u0.y);
    }
    ((uint2*)out)[(size_t)node * 64 + lane] = make_uint2(pack2(a0, a1), pack2(a2, a3));
  }
}

// ---------------- MFMA GEMM: C[M,256] = opA(A[M,K]) @ Bt[256,K]^T + bias ----------------
// 128x128 tile, BK=64, 4 waves 2x2. 2-phase pipeline: prefetch K-tile t+1 into
// registers while tile t's MFMAs run; transform (BN+ReLU of prev layer) applied
// at load time so its VALU hides under MFMA. LDS 16B chunks XOR-swizzled by row&7.
template <int K, bool TRANSFORM, bool RELU_OUT, bool COLSUMS>
__global__ __launch_bounds__(256)
void k_gemm(const u16* __restrict__ A, const u16* __restrict__ Bt,
            const float* __restrict__ bias, const float* __restrict__ ta,
            const float* __restrict__ tc, u16* __restrict__ C,
            float* __restrict__ csum, float* __restrict__ csq) {
  __shared__ u16 As[128 * 64];
  __shared__ u16 Bs[128 * 64];
  const int tid = threadIdx.x;
  const int lane = tid & 63;
  const int w = tid >> 6;
  const int wm = w >> 1, wn = w & 1;
  const int lr = lane & 15, lq = lane >> 4;
  const int r0 = blockIdx.x * 128;
  const int n0 = blockIdx.y * 128;
  const int sm = tid >> 1;            // staging row 0..127 (2 threads/row)
  const int sq0 = (tid & 1) * 4;      // staging chunk base 0 or 4

  f32x4 acc[4][4];
#pragma unroll
  for (int i = 0; i < 4; ++i)
#pragma unroll
    for (int j = 0; j < 4; ++j) acc[i][j] = (f32x4){0.f, 0.f, 0.f, 0.f};

  short8 va[4], vb[4];

  // load (and transform) one K-tile into registers
  auto LOAD = [&](int k0) {
    int gm = r0 + sm;
#pragma unroll
    for (int c = 0; c < 4; ++c) {
      int q = sq0 + c;
      short8 v = (short8)0;
      if (gm < NN) {
        v = *(const short8*)&A[(size_t)gm * K + k0 + q * 8];
        if constexpr (TRANSFORM) {
#pragma unroll
          for (int j = 0; j < 8; ++j) {
            float f = __uint_as_float(((u32)(u16)v[j]) << 16);
            float tv = fmaxf(fmaf(f, ta[k0 + q * 8 + j], tc[k0 + q * 8 + j]), 0.f);
            v[j] = (short)f2bf(tv);
          }
        }
      }
      va[c] = v;
      vb[c] = *(const short8*)&Bt[(size_t)(n0 + sm) * K + k0 + q * 8];
    }
  };
  auto STORE = [&]() {
#pragma unroll
    for (int c = 0; c < 4; ++c) {
      int q = sq0 + c;
      ((short8*)As)[sm * 8 + (q ^ (sm & 7))] = va[c];
      ((short8*)Bs)[sm * 8 + (q ^ (sm & 7))] = vb[c];
    }
  };

  LOAD(0);
  constexpr int NT = K / 64;
#pragma unroll
  for (int t = 0; t < NT; ++t) {
    STORE();
    __syncthreads();
    if (t + 1 < NT) LOAD((t + 1) * 64);   // in flight during MFMAs below
#pragma unroll
    for (int ks = 0; ks < 2; ++ks) {
      short8 af[4], bfr[4];
#pragma unroll
      for (int mi = 0; mi < 4; ++mi) {
        int row = wm * 64 + mi * 16 + lr;
        int ch = (ks * 4 + lq) ^ (row & 7);
        af[mi] = ((const short8*)As)[row * 8 + ch];
      }
#pragma unroll
      for (int ni = 0; ni < 4; ++ni) {
        int row = wn * 64 + ni * 16 + lr;
        int ch = (ks * 4 + lq) ^ (row & 7);
        bfr[ni] = ((const short8*)Bs)[row * 8 + ch];
      }
#pragma unroll
      for (int mi = 0; mi < 4; ++mi)
#pragma unroll
        for (int ni = 0; ni < 4; ++ni)
          acc[mi][ni] = __builtin_amdgcn_mfma_f32_16x16x32_bf16(af[mi], bfr[ni], acc[mi][ni], 0, 0, 0);
    }
    __syncthreads();
  }

  // epilogue: C/D layout col=lane&15, row=lq*4+reg
  float colS[4] = {}, colQ[4] = {};
#pragma unroll
  for (int ni = 0; ni < 4; ++ni) {
    int col = n0 + wn * 64 + ni * 16 + lr;
    float bv = bias[col];
#pragma unroll
    for (int mi = 0; mi < 4; ++mi) {
      int rbase = r0 + wm * 64 + mi * 16 + lq * 4;
#pragma unroll
      for (int j = 0; j < 4; ++j) {
        int row = rbase + j;
        if (row < NN) {
          float v = acc[mi][ni][j] + bv;
          if constexpr (RELU_OUT) v = fmaxf(v, 0.f);
          C[(size_t)row * HDIM + col] = f2bf(v);
          if constexpr (COLSUMS) { colS[ni] += v; colQ[ni] += v * v; }
        }
      }
    }
  }
  if constexpr (COLSUMS) {
#pragma unroll
    for (int ni = 0; ni < 4; ++ni) {
      float s = colS[ni], q = colQ[ni];
      s += __shfl_xor(s, 16); s += __shfl_xor(s, 32);
      q += __shfl_xor(q, 16); q += __shfl_xor(q, 32);
      if (lq == 0) {
        int col = n0 + wn * 64 + ni * 16 + lr;
        atomicAdd(&csum[col], s);
        atomicAdd(&csq[col], q);
      }
    }
  }
}

// ---------------- BN finalize ----------------
__global__ void k_bn_fin(const float* __restrict__ sum, const float* __restrict__ sq,
                         const float* __restrict__ g, const float* __restrict__ be,
                         float* __restrict__ a, float* __restrict__ c) {
  int t = threadIdx.x;
  float m = sum[t] * (1.0f / NN);
  float var = sq[t] * (1.0f / NN) - m * m;
  float s = g[t] * rsqrtf(var + BN_EPS);
  a[t] = s;
  c[t] = be[t] - m * s;
}

// ---------------- final GEMM: out[NN,40] = relu(z*ta+tc) @ Wf + bf (fp32 vector) ----------------
__global__ __launch_bounds__(256)
void k_gemm_final(const u16* __restrict__ A, const float* __restrict__ B,
                  const float* __restrict__ bias, const float* __restrict__ ta,
                  const float* __restrict__ tc, float* __restrict__ C) {
  __shared__ float As[64][65];
  __shared__ float Bs[64][CDIM];
  int tid = threadIdx.x;
  int r = tid & 63, q = tid >> 6;
  int r0 = blockIdx.x * 64;
  float acc[10] = {};
  for (int k0 = 0; k0 < HDIM; k0 += 64) {
#pragma unroll
    for (int i = 0; i < 4; ++i) {
      int idx = tid + i * 256;
      int row = idx >> 4;
      int c4 = (idx & 15) * 4;
      int gr = r0 + row;
      float v0 = 0.f, v1 = 0.f, v2 = 0.f, v3 = 0.f;
      if (gr < NN) {
        uint2 u = *(const uint2*)&A[(size_t)gr * HDIM + k0 + c4];
        v0 = fmaxf(fmaf(bflo(u.x), ta[k0 + c4 + 0], tc[k0 + c4 + 0]), 0.f);
        v1 = fmaxf(fmaf(bfhi(u.x), ta[k0 + c4 + 1], tc[k0 + c4 + 1]), 0.f);
        v2 = fmaxf(fmaf(bflo(u.y), ta[k0 + c4 + 2], tc[k0 + c4 + 2]), 0.f);
        v3 = fmaxf(fmaf(bfhi(u.y), ta[k0 + c4 + 3], tc[k0 + c4 + 3]), 0.f);
      }
      As[c4 + 0][row] = v0;
      As[c4 + 1][row] = v1;
      As[c4 + 2][row] = v2;
      As[c4 + 3][row] = v3;
    }
#pragma unroll
    for (int i = 0; i < 10; ++i) {
      int idx = tid + i * 256;
      int row = idx / CDIM;
      int col = idx % CDIM;
      Bs[row][col] = B[(size_t)(k0 + row) * CDIM + col];
    }
    __syncthreads();
#pragma unroll
    for (int k = 0; k < 64; ++k) {
      float a = As[k][r];
#pragma unroll
      for (int j = 0; j < 10; ++j) acc[j] = fmaf(a, Bs[k][q * 10 + j], acc[j]);
    }
    __syncthreads();
  }
  int gr = r0 + r;
  if (gr < NN) {
#pragma unroll
    for (int j = 0; j < 10; ++j) C[(size_t)gr * CDIM + q * 10 + j] = acc[j] + bias[q * 10 + j];
  }
}

// ---------------- launch ----------------
extern "C" void kernel_launch(void* const* d_in, const int* in_sizes, int n_in,
                              void* d_out, int out_size, void* d_ws, size_t ws_size,
                              hipStream_t stream) {
  const float* x   = (const float*)d_in[0];
  const int*   ei  = (const int*)d_in[1];
  const float* eps1= (const float*)d_in[2];
  const float* W1  = (const float*)d_in[3];
  const float* b1  = (const float*)d_in[4];
  const float* g1  = (const float*)d_in[5];
  const float* be1 = (const float*)d_in[6];
  const float* W2  = (const float*)d_in[7];
  const float* b2  = (const float*)d_in[8];
  const float* eps2= (const float*)d_in[9];
  const float* W3  = (const float*)d_in[10];
  const float* b3  = (const float*)d_in[11];
  const float* g2  = (const float*)d_in[12];
  const float* be2 = (const float*)d_in[13];
  const float* W4  = (const float*)d_in[14];
  const float* b4  = (const float*)d_in[15];
  const float* g3  = (const float*)d_in[16];
  const float* be3 = (const float*)d_in[17];
  const float* Wf  = (const float*)d_in[18];
  const float* bf  = (const float*)d_in[19];
  float* out = (float*)d_out;

  char* p = (char*)d_ws;
  auto alloc = [&](size_t bytes) -> char* {
    char* r = p;
    p += (bytes + 255) & ~(size_t)255;
    return r;
  };
  float* stats   = (float*)alloc(12 * 256 * sizeof(float));
  int* deg       = (int*)alloc(NN * sizeof(int));
  int* rowstart  = (int*)alloc((NN + 16) * sizeof(int));
  int* cursor    = (int*)alloc(NN * sizeof(int));
  int* sorted    = (int*)alloc(EE * sizeof(int));
  int* partial   = (int*)alloc(NN * sizeof(int));
  int* bsums     = (int*)alloc(1024 * sizeof(int));
  u16* W1t       = (u16*)alloc(256 * 128 * sizeof(u16));
  u16* W2t       = (u16*)alloc(256 * 256 * sizeof(u16));
  u16* W3t       = (u16*)alloc(256 * 256 * sizeof(u16));
  u16* W4t       = (u16*)alloc(256 * 256 * sizeof(u16));
  u16* xb        = (u16*)alloc((size_t)NN * 128 * sizeof(u16));
  u16* A1        = (u16*)alloc((size_t)NN * 128 * sizeof(u16));
  u16* z1        = (u16*)alloc((size_t)NN * 256 * sizeof(u16));
  u16* h1        = (u16*)alloc((size_t)NN * 256 * sizeof(u16));
  u16* A2        = (u16*)alloc((size_t)NN * 256 * sizeof(u16));
  u16* z2 = z1;  // z1 dead after gemm2
  u16* z3 = h1;  // h1 dead after agg2

  hipMemsetAsync(deg, 0, NN * sizeof(int), stream);
  hipMemsetAsync(stats, 0, 12 * 256 * sizeof(float), stream);

  const int nbE = (EE + 255) / 256;
  const int nbN = (NN + 255) / 256;

  k_hist<<<nbE, 256, 0, stream>>>(ei, deg);
  k_scan_blocks<<<nbN, 256, 0, stream>>>(deg, partial, bsums, NN);
  k_scan_sums<<<1, 256, 0, stream>>>(bsums, nbN);
  k_scan_add<<<nbN, 256, 0, stream>>>(partial, bsums, rowstart, NN);
  k_copy_i32<<<nbN, 256, 0, stream>>>(rowstart, cursor, NN);
  k_scatter<<<nbE, 256, 0, stream>>>(ei, cursor, sorted);

  k_cvt_x<<<(NN * FDIM / 4 + 255) / 256, 256, 0, stream>>>(x, xb);
  k_cvt_wt<<<128, 256, 0, stream>>>(W1, W1t, 128);
  k_cvt_wt<<<256, 256, 0, stream>>>(W2, W2t, 256);
  k_cvt_wt<<<256, 256, 0, stream>>>(W3, W3t, 256);
  k_cvt_wt<<<256, 256, 0, stream>>>(W4, W4t, 256);

  dim3 gG((NN + 127) / 128, 2);

  // conv1
  k_agg<128><<<(NN + 3) / 4, 256, 0, stream>>>(xb, rowstart, sorted, eps1, A1);
  k_gemm<128, false, false, true><<<gG, 256, 0, stream>>>(
      A1, W1t, b1, nullptr, nullptr, z1, stats + 0, stats + 256);
  k_bn_fin<<<1, 256, 0, stream>>>(stats + 0, stats + 256, g1, be1,
                                  stats + 2 * 256, stats + 3 * 256);
  k_gemm<256, true, true, false><<<gG, 256, 0, stream>>>(
      z1, W2t, b2, stats + 2 * 256, stats + 3 * 256, h1, nullptr, nullptr);

  // conv2
  k_agg<256><<<(NN + 3) / 4, 256, 0, stream>>>(h1, rowstart, sorted, eps2, A2);
  k_gemm<256, false, false, true><<<gG, 256, 0, stream>>>(
      A2, W3t, b3, nullptr, nullptr, z2, stats + 4 * 256, stats + 5 * 256);
  k_bn_fin<<<1, 256, 0, stream>>>(stats + 4 * 256, stats + 5 * 256, g2, be2,
                                  stats + 6 * 256, stats + 7 * 256);
  k_gemm<256, true, false, true><<<gG, 256, 0, stream>>>(
      z2, W4t, b4, stats + 6 * 256, stats + 7 * 256, z3, stats + 8 * 256, stats + 9 * 256);
  k_bn_fin<<<1, 256, 0, stream>>>(stats + 8 * 256, stats + 9 * 256, g3, be3,
                                  stats + 10 * 256, stats + 11 * 256);

  // bn2+relu fused into final GEMM
  k_gemm_final<<<(NN + 63) / 64, 256, 0, stream>>>(
      z3, Wf, bf, stats + 10 * 256, stats + 11 * 256, out);
}

// Round 4
// 396.994 us; speedup vs baseline: 1.9021x; 1.2412x over previous
//
#include <hip/hip_runtime.h>
#include <hip/hip_bf16.h>

// GIN forward, MI355X. Barrier-free-K GEMM (B panel resident in LDS),
// direct global->reg A fragments, LDS-staged C writes, bf16 CSR aggregation.

#define NN 50000
#define EE 800000
#define FDIM 128
#define HDIM 256
#define CDIM 40
#define BN_EPS 1e-5f
#define CSTRIDE 136   // Cs row stride in u16 (128 cols + 8 pad -> 4-bank row shift)

typedef unsigned short u16;
typedef unsigned int u32;
typedef __attribute__((ext_vector_type(8))) short short8;
typedef __attribute__((ext_vector_type(4))) float f32x4;

__device__ __forceinline__ float bflo(u32 u) { return __uint_as_float(u << 16); }
__device__ __forceinline__ float bfhi(u32 u) { return __uint_as_float(u & 0xFFFF0000u); }
__device__ __forceinline__ u16 f2bf(float f) {
  __hip_bfloat16 h = __float2bfloat16(f);
  return *(u16*)&h;
}
__device__ __forceinline__ u32 pack2(float a, float b) {
  return (u32)f2bf(a) | ((u32)f2bf(b) << 16);
}

// ---------------- CSR build ----------------
__global__ void k_hist(const int* __restrict__ ei, int* __restrict__ deg) {
  int e = blockIdx.x * 256 + threadIdx.x;
  if (e < EE) atomicAdd(&deg[ei[EE + e]], 1);
}

__global__ void k_scan_blocks(const int* __restrict__ in, int* __restrict__ partial,
                              int* __restrict__ bsums, int n) {
  __shared__ int s[256];
  int i = blockIdx.x * 256 + threadIdx.x;
  s[threadIdx.x] = (i < n) ? in[i] : 0;
  __syncthreads();
  for (int d = 1; d < 256; d <<= 1) {
    int t = (threadIdx.x >= d) ? s[threadIdx.x - d] : 0;
    __syncthreads();
    s[threadIdx.x] += t;
    __syncthreads();
  }
  if (i < n) partial[i] = s[threadIdx.x];
  if (threadIdx.x == 255) bsums[blockIdx.x] = s[255];
}

__global__ void k_scan_sums(int* __restrict__ bs, int nb) {
  __shared__ int s[256];
  s[threadIdx.x] = (threadIdx.x < nb) ? bs[threadIdx.x] : 0;
  __syncthreads();
  for (int d = 1; d < 256; d <<= 1) {
    int t = (threadIdx.x >= d) ? s[threadIdx.x - d] : 0;
    __syncthreads();
    s[threadIdx.x] += t;
    __syncthreads();
  }
  int ex = (threadIdx.x == 0) ? 0 : s[threadIdx.x - 1];
  if (threadIdx.x < nb) bs[threadIdx.x] = ex;
}

__global__ void k_scan_add(const int* __restrict__ partial, const int* __restrict__ bs,
                           int* __restrict__ rowstart, int n) {
  int i = blockIdx.x * 256 + threadIdx.x;
  if (i < n) rowstart[i + 1] = partial[i] + bs[blockIdx.x];
  if (i == 0) rowstart[0] = 0;
}

__global__ void k_copy_i32(const int* __restrict__ a, int* __restrict__ b, int n) {
  int i = blockIdx.x * 256 + threadIdx.x;
  if (i < n) b[i] = a[i];
}

__global__ void k_scatter(const int* __restrict__ ei, int* __restrict__ cursor,
                          int* __restrict__ sorted_src) {
  int e = blockIdx.x * 256 + threadIdx.x;
  if (e < EE) {
    int dst = ei[EE + e];
    int p = atomicAdd(&cursor[dst], 1);
    sorted_src[p] = ei[e];
  }
}

// ---------------- conversions ----------------
__global__ void k_cvt_x(const float* __restrict__ x, u16* __restrict__ xb) {
  int i = blockIdx.x * 256 + threadIdx.x;
  size_t base = (size_t)i * 4;
  if (base < (size_t)NN * FDIM) {
    float4 v = *(const float4*)&x[base];
    u32 lo = pack2(v.x, v.y), hi = pack2(v.z, v.w);
    *(uint2*)&xb[base] = make_uint2(lo, hi);
  }
}

// W [K,256] fp32 -> Wt [256,K] bf16 (transpose)
__global__ void k_cvt_wt(const float* __restrict__ W, u16* __restrict__ Wt, int K) {
  int i = blockIdx.x * 256 + threadIdx.x;
  int k = i >> 8, n = i & 255;
  if (k < K) Wt[(size_t)n * K + k] = f2bf(W[i]);
}

// ---------------- aggregation (bf16 in/out, f32 accumulate, 4-deep MLP) ----------------
template <int FEAT>
__global__ __launch_bounds__(256)
void k_agg(const u16* __restrict__ x, const int* __restrict__ rowstart,
           const int* __restrict__ sorted_src, const float* __restrict__ epsp,
           u16* __restrict__ out) {
  int node = blockIdx.x * 4 + (threadIdx.x >> 6);
  if (node >= NN) return;
  int lane = threadIdx.x & 63;
  float e1 = 1.0f + epsp[0];
  int s = rowstart[node], t = rowstart[node + 1];
  if constexpr (FEAT == 128) {
    const u32* xp = (const u32*)x;
    u32 u = xp[(size_t)node * 64 + lane];
    float a0 = bflo(u) * e1, a1 = bfhi(u) * e1;
    int p = s;
    for (; p + 3 < t; p += 4) {
      int s0 = sorted_src[p], s1 = sorted_src[p + 1];
      int s2 = sorted_src[p + 2], s3 = sorted_src[p + 3];
      u32 u0 = xp[(size_t)s0 * 64 + lane];
      u32 u1 = xp[(size_t)s1 * 64 + lane];
      u32 u2 = xp[(size_t)s2 * 64 + lane];
      u32 u3 = xp[(size_t)s3 * 64 + lane];
      a0 += (bflo(u0) + bflo(u1)) + (bflo(u2) + bflo(u3));
      a1 += (bfhi(u0) + bfhi(u1)) + (bfhi(u2) + bfhi(u3));
    }
    for (; p < t; ++p) {
      u32 u0 = xp[(size_t)sorted_src[p] * 64 + lane];
      a0 += bflo(u0); a1 += bfhi(u0);
    }
    ((u32*)out)[(size_t)node * 64 + lane] = pack2(a0, a1);
  } else {
    const uint2* xp = (const uint2*)x;
    uint2 u = xp[(size_t)node * 64 + lane];
    float a0 = bflo(u.x) * e1, a1 = bfhi(u.x) * e1;
    float a2 = bflo(u.y) * e1, a3 = bfhi(u.y) * e1;
    int p = s;
    for (; p + 3 < t; p += 4) {
      int s0 = sorted_src[p], s1 = sorted_src[p + 1];
      int s2 = sorted_src[p + 2], s3 = sorted_src[p + 3];
      uint2 u0 = xp[(size_t)s0 * 64 + lane];
      uint2 u1 = xp[(size_t)s1 * 64 + lane];
      uint2 u2 = xp[(size_t)s2 * 64 + lane];
      uint2 u3 = xp[(size_t)s3 * 64 + lane];
      a0 += (bflo(u0.x) + bflo(u1.x)) + (bflo(u2.x) + bflo(u3.x));
      a1 += (bfhi(u0.x) + bfhi(u1.x)) + (bfhi(u2.x) + bfhi(u3.x));
      a2 += (bflo(u0.y) + bflo(u1.y)) + (bflo(u2.y) + bflo(u3.y));
      a3 += (bfhi(u0.y) + bfhi(u1.y)) + (bfhi(u2.y) + bfhi(u3.y));
    }
    for (; p < t; ++p) {
      uint2 u0 = xp[(size_t)sorted_src[p] * 64 + lane];
      a0 += bflo(u0.x); a1 += bfhi(u0.x);
      a2 += bflo(u0.y); a3 += bfhi(u0.y);
    }
    ((uint2*)out)[(size_t)node * 64 + lane] = make_uint2(pack2(a0, a1), pack2(a2, a3));
  }
}

// ---------------- MFMA GEMM: C[M,256] = opA(A[M,K]) @ Bt[256,K]^T + bias ----------------
// Persistent: 512 blocks x 256 thr (4 waves). Each block owns a 128-col half of B,
// staged ONCE into LDS (swizzled). K-loop is barrier-free: A fragments load
// direct global->reg (8 independent 16B loads upfront), B fragments via
// conflict-free ds_read_b128. C staged in LDS, copied out as full 32B/lane lines.
template <int K, bool TRANSFORM, bool RELU_OUT, bool COLSUMS>
__global__ __launch_bounds__(256)
void k_gemm(const u16* __restrict__ A, const u16* __restrict__ Bt,
            const float* __restrict__ bias, const float* __restrict__ ta,
            const float* __restrict__ tc, u16* __restrict__ C,
            float* __restrict__ csum, float* __restrict__ csq) {
  constexpr int NCH = K / 8;    // 16B chunks per K-row
  constexpr int NKS = K / 32;   // MFMA k-steps
  __shared__ u16 Bs[128 * K];          // half of B^T, swizzled
  __shared__ u16 Cs[32 * CSTRIDE];     // C staging tile (32 rows x 128 cols + pad)
  __shared__ float2 Tb[K];             // {ta,tc} pairs (TRANSFORM only)

  const int tid = threadIdx.x;
  const int lane = tid & 63;
  const int w = tid >> 6;          // 0..3
  const int wm = w >> 1;           // 0..1 : 16-row group
  const int wn = w & 1;            // 0..1 : 64-col group
  const int lr = lane & 15, lq = lane >> 4;
  const int half = blockIdx.x & 1;          // which 128 cols of B
  const u16* Bth = Bt + (size_t)half * 128 * K;

  // stage B half into LDS (16B chunks, XOR-swizzle by row&7)
  for (int i = tid; i < 128 * NCH; i += 256) {
    int row = i / NCH, c = i % NCH;
    short8 v = *(const short8*)&Bth[(size_t)row * K + c * 8];
    ((short8*)Bs)[row * NCH + (c ^ (row & 7))] = v;
  }
  if constexpr (TRANSFORM) {
    for (int k = tid; k < K; k += 256) Tb[k] = make_float2(ta[k], tc[k]);
  }

  float bv[4];
#pragma unroll
  for (int ni = 0; ni < 4; ++ni) bv[ni] = bias[half * 128 + wn * 64 + ni * 16 + lr];
  float colS[4] = {}, colQ[4] = {};

  __syncthreads();

  constexpr int NTILE = (NN + 31) / 32;   // 1563
  for (int rt = blockIdx.x >> 1; rt < NTILE; rt += 256) {
    int row = rt * 32 + wm * 16 + lr;
    int rowc = row < NN ? row : NN - 1;
    const u16* Ap = &A[(size_t)rowc * K];

    // A fragments: NKS independent 16B loads, all in flight at once
    short8 areg[NKS];
#pragma unroll
    for (int ks = 0; ks < NKS; ++ks)
      areg[ks] = *(const short8*)&Ap[ks * 32 + lq * 8];

    if constexpr (TRANSFORM) {
#pragma unroll
      for (int ks = 0; ks < NKS; ++ks) {
        short8 v = areg[ks];
#pragma unroll
        for (int j = 0; j < 8; ++j) {
          float2 tb = Tb[ks * 32 + lq * 8 + j];   // LDS broadcast read
          float f = __uint_as_float(((u32)(u16)v[j]) << 16);
          v[j] = (short)f2bf(fmaxf(fmaf(f, tb.x, tb.y), 0.f));
        }
        areg[ks] = v;
      }
    }

    f32x4 acc[4];
#pragma unroll
    for (int ni = 0; ni < 4; ++ni) acc[ni] = (f32x4){0.f, 0.f, 0.f, 0.f};
#pragma unroll
    for (int ks = 0; ks < NKS; ++ks) {
#pragma unroll
      for (int ni = 0; ni < 4; ++ni) {
        int col = wn * 64 + ni * 16 + lr;
        int c = (ks * 4 + lq) ^ (col & 7);
        short8 bfr = ((const short8*)Bs)[col * NCH + c];
        acc[ni] = __builtin_amdgcn_mfma_f32_16x16x32_bf16(areg[ks], bfr, acc[ni], 0, 0, 0);
      }
    }

    // epilogue: bias (+relu) -> colsums -> stage to Cs
#pragma unroll
    for (int ni = 0; ni < 4; ++ni) {
      int col = wn * 64 + ni * 16 + lr;
#pragma unroll
      for (int j = 0; j < 4; ++j) {
        int r = wm * 16 + lq * 4 + j;
        float v = acc[ni][j] + bv[ni];
        if constexpr (RELU_OUT) v = fmaxf(v, 0.f);
        if constexpr (COLSUMS) {
          if (rt * 32 + r < NN) { colS[ni] += v; colQ[ni] += v * v; }
        }
        Cs[r * CSTRIDE + col] = f2bf(v);
      }
    }
    __syncthreads();
    // copy out: thread t -> row t>>3, 32B at (t&7)*32
    {
      int r = tid >> 3;
      int gr = rt * 32 + r;
      if (gr < NN) {
        const uint4* src = (const uint4*)&Cs[r * CSTRIDE + (tid & 7) * 16];
        uint4 v0 = src[0], v1 = src[1];
        uint4* dst = (uint4*)&C[(size_t)gr * HDIM + half * 128 + (tid & 7) * 16];
        dst[0] = v0; dst[1] = v1;
      }
    }
    __syncthreads();
  }

  if constexpr (COLSUMS) {
#pragma unroll
    for (int ni = 0; ni < 4; ++ni) {
      float s = colS[ni], q = colQ[ni];
      s += __shfl_xor(s, 16); s += __shfl_xor(s, 32);
      q += __shfl_xor(q, 16); q += __shfl_xor(q, 32);
      if (lq == 0) {
        int col = half * 128 + wn * 64 + ni * 16 + lr;
        atomicAdd(&csum[col], s);
        atomicAdd(&csq[col], q);
      }
    }
  }
}

// ---------------- BN finalize ----------------
__global__ void k_bn_fin(const float* __restrict__ sum, const float* __restrict__ sq,
                         const float* __restrict__ g, const float* __restrict__ be,
                         float* __restrict__ a, float* __restrict__ c) {
  int t = threadIdx.x;
  float m = sum[t] * (1.0f / NN);
  float var = sq[t] * (1.0f / NN) - m * m;
  float s = g[t] * rsqrtf(var + BN_EPS);
  a[t] = s;
  c[t] = be[t] - m * s;
}

// ---------------- final GEMM: out[NN,40] = relu(z*ta+tc) @ Wf + bf (fp32 vector) ----------------
__global__ __launch_bounds__(256)
void k_gemm_final(const u16* __restrict__ A, const float* __restrict__ B,
                  const float* __restrict__ bias, const float* __restrict__ ta,
                  const float* __restrict__ tc, float* __restrict__ C) {
  __shared__ float As[64][65];
  __shared__ float Bs[64][CDIM];
  int tid = threadIdx.x;
  int r = tid & 63, q = tid >> 6;
  int r0 = blockIdx.x * 64;
  float acc[10] = {};
  for (int k0 = 0; k0 < HDIM; k0 += 64) {
#pragma unroll
    for (int i = 0; i < 4; ++i) {
      int idx = tid + i * 256;
      int row = idx >> 4;
      int c4 = (idx & 15) * 4;
      int gr = r0 + row;
      float v0 = 0.f, v1 = 0.f, v2 = 0.f, v3 = 0.f;
      if (gr < NN) {
        uint2 u = *(const uint2*)&A[(size_t)gr * HDIM + k0 + c4];
        v0 = fmaxf(fmaf(bflo(u.x), ta[k0 + c4 + 0], tc[k0 + c4 + 0]), 0.f);
        v1 = fmaxf(fmaf(bfhi(u.x), ta[k0 + c4 + 1], tc[k0 + c4 + 1]), 0.f);
        v2 = fmaxf(fmaf(bflo(u.y), ta[k0 + c4 + 2], tc[k0 + c4 + 2]), 0.f);
        v3 = fmaxf(fmaf(bfhi(u.y), ta[k0 + c4 + 3], tc[k0 + c4 + 3]), 0.f);
      }
      As[c4 + 0][row] = v0;
      As[c4 + 1][row] = v1;
      As[c4 + 2][row] = v2;
      As[c4 + 3][row] = v3;
    }
#pragma unroll
    for (int i = 0; i < 10; ++i) {
      int idx = tid + i * 256;
      int row = idx / CDIM;
      int col = idx % CDIM;
      Bs[row][col] = B[(size_t)(k0 + row) * CDIM + col];
    }
    __syncthreads();
#pragma unroll
    for (int k = 0; k < 64; ++k) {
      float a = As[k][r];
#pragma unroll
      for (int j = 0; j < 10; ++j) acc[j] = fmaf(a, Bs[k][q * 10 + j], acc[j]);
    }
    __syncthreads();
  }
  int gr = r0 + r;
  if (gr < NN) {
#pragma unroll
    for (int j = 0; j < 10; ++j) C[(size_t)gr * CDIM + q * 10 + j] = acc[j] + bias[q * 10 + j];
  }
}

// ---------------- launch ----------------
extern "C" void kernel_launch(void* const* d_in, const int* in_sizes, int n_in,
                              void* d_out, int out_size, void* d_ws, size_t ws_size,
                              hipStream_t stream) {
  const float* x   = (const float*)d_in[0];
  const int*   ei  = (const int*)d_in[1];
  const float* eps1= (const float*)d_in[2];
  const float* W1  = (const float*)d_in[3];
  const float* b1  = (const float*)d_in[4];
  const float* g1  = (const float*)d_in[5];
  const float* be1 = (const float*)d_in[6];
  const float* W2  = (const float*)d_in[7];
  const float* b2  = (const float*)d_in[8];
  const float* eps2= (const float*)d_in[9];
  const float* W3  = (const float*)d_in[10];
  const float* b3  = (const float*)d_in[11];
  const float* g2  = (const float*)d_in[12];
  const float* be2 = (const float*)d_in[13];
  const float* W4  = (const float*)d_in[14];
  const float* b4  = (const float*)d_in[15];
  const float* g3  = (const float*)d_in[16];
  const float* be3 = (const float*)d_in[17];
  const float* Wf  = (const float*)d_in[18];
  const float* bf  = (const float*)d_in[19];
  float* out = (float*)d_out;

  char* p = (char*)d_ws;
  auto alloc = [&](size_t bytes) -> char* {
    char* r = p;
    p += (bytes + 255) & ~(size_t)255;
    return r;
  };
  float* stats   = (float*)alloc(12 * 256 * sizeof(float));
  int* deg       = (int*)alloc(NN * sizeof(int));
  int* rowstart  = (int*)alloc((NN + 16) * sizeof(int));
  int* cursor    = (int*)alloc(NN * sizeof(int));
  int* sorted    = (int*)alloc(EE * sizeof(int));
  int* partial   = (int*)alloc(NN * sizeof(int));
  int* bsums     = (int*)alloc(1024 * sizeof(int));
  u16* W1t       = (u16*)alloc(256 * 128 * sizeof(u16));
  u16* W2t       = (u16*)alloc(256 * 256 * sizeof(u16));
  u16* W3t       = (u16*)alloc(256 * 256 * sizeof(u16));
  u16* W4t       = (u16*)alloc(256 * 256 * sizeof(u16));
  u16* xb        = (u16*)alloc((size_t)NN * 128 * sizeof(u16));
  u16* A1        = (u16*)alloc((size_t)NN * 128 * sizeof(u16));
  u16* z1        = (u16*)alloc((size_t)NN * 256 * sizeof(u16));
  u16* h1        = (u16*)alloc((size_t)NN * 256 * sizeof(u16));
  u16* A2        = (u16*)alloc((size_t)NN * 256 * sizeof(u16));
  (void)alloc(64 * 1024);  // guard pad for clamped OOB-adjacent reads
  u16* z2 = z1;  // z1 dead after gemm2
  u16* z3 = h1;  // h1 dead after agg2

  hipMemsetAsync(deg, 0, NN * sizeof(int), stream);
  hipMemsetAsync(stats, 0, 12 * 256 * sizeof(float), stream);

  const int nbE = (EE + 255) / 256;
  const int nbN = (NN + 255) / 256;

  k_hist<<<nbE, 256, 0, stream>>>(ei, deg);
  k_scan_blocks<<<nbN, 256, 0, stream>>>(deg, partial, bsums, NN);
  k_scan_sums<<<1, 256, 0, stream>>>(bsums, nbN);
  k_scan_add<<<nbN, 256, 0, stream>>>(partial, bsums, rowstart, NN);
  k_copy_i32<<<nbN, 256, 0, stream>>>(rowstart, cursor, NN);
  k_scatter<<<nbE, 256, 0, stream>>>(ei, cursor, sorted);

  k_cvt_x<<<(NN * FDIM / 4 + 255) / 256, 256, 0, stream>>>(x, xb);
  k_cvt_wt<<<128, 256, 0, stream>>>(W1, W1t, 128);
  k_cvt_wt<<<256, 256, 0, stream>>>(W2, W2t, 256);
  k_cvt_wt<<<256, 256, 0, stream>>>(W3, W3t, 256);
  k_cvt_wt<<<256, 256, 0, stream>>>(W4, W4t, 256);

  // conv1
  k_agg<128><<<(NN + 3) / 4, 256, 0, stream>>>(xb, rowstart, sorted, eps1, A1);
  k_gemm<128, false, false, true><<<512, 256, 0, stream>>>(
      A1, W1t, b1, nullptr, nullptr, z1, stats + 0, stats + 256);
  k_bn_fin<<<1, 256, 0, stream>>>(stats + 0, stats + 256, g1, be1,
                                  stats + 2 * 256, stats + 3 * 256);
  k_gemm<256, true, true, false><<<512, 256, 0, stream>>>(
      z1, W2t, b2, stats + 2 * 256, stats + 3 * 256, h1, nullptr, nullptr);

  // conv2
  k_agg<256><<<(NN + 3) / 4, 256, 0, stream>>>(h1, rowstart, sorted, eps2, A2);
  k_gemm<256, false, false, true><<<512, 256, 0, stream>>>(
      A2, W3t, b3, nullptr, nullptr, z2, stats + 4 * 256, stats + 5 * 256);
  k_bn_fin<<<1, 256, 0, stream>>>(stats + 4 * 256, stats + 5 * 256, g2, be2,
                                  stats + 6 * 256, stats + 7 * 256);
  k_gemm<256, true, false, true><<<512, 256, 0, stream>>>(
      z2, W4t, b4, stats + 6 * 256, stats + 7 * 256, z3, stats + 8 * 256, stats + 9 * 256);
  k_bn_fin<<<1, 256, 0, stream>>>(stats + 8 * 256, stats + 9 * 256, g3, be3,
                                  stats + 10 * 256, stats + 11 * 256);

  // bn2+relu fused into final GEMM
  k_gemm_final<<<(NN + 63) / 64, 256, 0, stream>>>(
      z3, Wf, bf, stats + 10 * 256, stats + 11 * 256, out);
}

// Round 5
// 391.397 us; speedup vs baseline: 1.9293x; 1.0143x over previous
//
#include <hip/hip_runtime.h>
#include <hip/hip_bf16.h>

// GIN forward, MI355X. Persistent B-resident GEMM with A-reg double-buffer,
// 8-deep unrolled bf16 CSR aggregation, BN fused into GEMMs.

#define NN 50000
#define EE 800000
#define FDIM 128
#define HDIM 256
#define CDIM 40
#define BN_EPS 1e-5f
#define CSTRIDE 136   // Cs row stride in u16

typedef unsigned short u16;
typedef unsigned int u32;
typedef __attribute__((ext_vector_type(8))) short short8;
typedef __attribute__((ext_vector_type(4))) float f32x4;

__device__ __forceinline__ float bflo(u32 u) { return __uint_as_float(u << 16); }
__device__ __forceinline__ float bfhi(u32 u) { return __uint_as_float(u & 0xFFFF0000u); }
__device__ __forceinline__ u16 f2bf(float f) {
  __hip_bfloat16 h = __float2bfloat16(f);
  return *(u16*)&h;
}
__device__ __forceinline__ u32 pack2(float a, float b) {
  return (u32)f2bf(a) | ((u32)f2bf(b) << 16);
}

// ---------------- CSR build ----------------
__global__ void k_hist(const int* __restrict__ ei, int* __restrict__ deg) {
  int e = blockIdx.x * 256 + threadIdx.x;
  if (e < EE) atomicAdd(&deg[ei[EE + e]], 1);
}

__global__ void k_scan_blocks(const int* __restrict__ in, int* __restrict__ partial,
                              int* __restrict__ bsums, int n) {
  __shared__ int s[256];
  int i = blockIdx.x * 256 + threadIdx.x;
  s[threadIdx.x] = (i < n) ? in[i] : 0;
  __syncthreads();
  for (int d = 1; d < 256; d <<= 1) {
    int t = (threadIdx.x >= d) ? s[threadIdx.x - d] : 0;
    __syncthreads();
    s[threadIdx.x] += t;
    __syncthreads();
  }
  if (i < n) partial[i] = s[threadIdx.x];
  if (threadIdx.x == 255) bsums[blockIdx.x] = s[255];
}

__global__ void k_scan_sums(int* __restrict__ bs, int nb) {
  __shared__ int s[256];
  s[threadIdx.x] = (threadIdx.x < nb) ? bs[threadIdx.x] : 0;
  __syncthreads();
  for (int d = 1; d < 256; d <<= 1) {
    int t = (threadIdx.x >= d) ? s[threadIdx.x - d] : 0;
    __syncthreads();
    s[threadIdx.x] += t;
    __syncthreads();
  }
  int ex = (threadIdx.x == 0) ? 0 : s[threadIdx.x - 1];
  if (threadIdx.x < nb) bs[threadIdx.x] = ex;
}

__global__ void k_scan_add(const int* __restrict__ partial, const int* __restrict__ bs,
                           int* __restrict__ rowstart, int n) {
  int i = blockIdx.x * 256 + threadIdx.x;
  if (i < n) rowstart[i + 1] = partial[i] + bs[blockIdx.x];
  if (i == 0) rowstart[0] = 0;
}

__global__ void k_copy_i32(const int* __restrict__ a, int* __restrict__ b, int n) {
  int i = blockIdx.x * 256 + threadIdx.x;
  if (i < n) b[i] = a[i];
}

__global__ void k_scatter(const int* __restrict__ ei, int* __restrict__ cursor,
                          int* __restrict__ sorted_src) {
  int e = blockIdx.x * 256 + threadIdx.x;
  if (e < EE) {
    int dst = ei[EE + e];
    int p = atomicAdd(&cursor[dst], 1);
    sorted_src[p] = ei[e];
  }
}

// ---------------- conversions ----------------
__global__ void k_cvt_x(const float* __restrict__ x, u16* __restrict__ xb) {
  int i = blockIdx.x * 256 + threadIdx.x;
  size_t base = (size_t)i * 4;
  if (base < (size_t)NN * FDIM) {
    float4 v = *(const float4*)&x[base];
    u32 lo = pack2(v.x, v.y), hi = pack2(v.z, v.w);
    *(uint2*)&xb[base] = make_uint2(lo, hi);
  }
}

__global__ void k_cvt_wt(const float* __restrict__ W, u16* __restrict__ Wt, int K) {
  int i = blockIdx.x * 256 + threadIdx.x;
  int k = i >> 8, n = i & 255;
  if (k < K) Wt[(size_t)n * K + k] = f2bf(W[i]);
}

// ---------------- aggregation (bf16 in/out, f32 accumulate, 8-deep MLP) ----------------
template <int FEAT>
__global__ __launch_bounds__(256)
void k_agg(const u16* __restrict__ x, const int* __restrict__ rowstart,
           const int* __restrict__ sorted_src, const float* __restrict__ epsp,
           u16* __restrict__ out) {
  int node = blockIdx.x * 4 + (threadIdx.x >> 6);
  if (node >= NN) return;
  int lane = threadIdx.x & 63;
  float e1 = 1.0f + epsp[0];
  int s = rowstart[node], t = rowstart[node + 1];
  if constexpr (FEAT == 128) {
    const u32* xp = (const u32*)x;
    u32 u = xp[(size_t)node * 64 + lane];
    float a0 = bflo(u) * e1, a1 = bfhi(u) * e1;
    int p = s;
    for (; p + 7 < t; p += 8) {
      u32 uu[8];
#pragma unroll
      for (int i = 0; i < 8; ++i) uu[i] = xp[(size_t)sorted_src[p + i] * 64 + lane];
#pragma unroll
      for (int i = 0; i < 8; ++i) { a0 += bflo(uu[i]); a1 += bfhi(uu[i]); }
    }
    for (; p + 1 < t; p += 2) {
      u32 u0 = xp[(size_t)sorted_src[p] * 64 + lane];
      u32 u1 = xp[(size_t)sorted_src[p + 1] * 64 + lane];
      a0 += bflo(u0) + bflo(u1);
      a1 += bfhi(u0) + bfhi(u1);
    }
    if (p < t) {
      u32 u0 = xp[(size_t)sorted_src[p] * 64 + lane];
      a0 += bflo(u0); a1 += bfhi(u0);
    }
    ((u32*)out)[(size_t)node * 64 + lane] = pack2(a0, a1);
  } else {
    const uint2* xp = (const uint2*)x;
    uint2 u = xp[(size_t)node * 64 + lane];
    float a0 = bflo(u.x) * e1, a1 = bfhi(u.x) * e1;
    float a2 = bflo(u.y) * e1, a3 = bfhi(u.y) * e1;
    int p = s;
    for (; p + 7 < t; p += 8) {
      uint2 uu[8];
#pragma unroll
      for (int i = 0; i < 8; ++i) uu[i] = xp[(size_t)sorted_src[p + i] * 64 + lane];
#pragma unroll
      for (int i = 0; i < 8; ++i) {
        a0 += bflo(uu[i].x); a1 += bfhi(uu[i].x);
        a2 += bflo(uu[i].y); a3 += bfhi(uu[i].y);
      }
    }
    for (; p + 1 < t; p += 2) {
      uint2 u0 = xp[(size_t)sorted_src[p] * 64 + lane];
      uint2 u1 = xp[(size_t)sorted_src[p + 1] * 64 + lane];
      a0 += bflo(u0.x) + bflo(u1.x);
      a1 += bfhi(u0.x) + bfhi(u1.x);
      a2 += bflo(u0.y) + bflo(u1.y);
      a3 += bfhi(u0.y) + bfhi(u1.y);
    }
    if (p < t) {
      uint2 u0 = xp[(size_t)sorted_src[p] * 64 + lane];
      a0 += bflo(u0.x); a1 += bfhi(u0.x);
      a2 += bflo(u0.y); a3 += bfhi(u0.y);
    }
    ((uint2*)out)[(size_t)node * 64 + lane] = make_uint2(pack2(a0, a1), pack2(a2, a3));
  }
}

// ---------------- MFMA GEMM: C[M,256] = opA(A[M,K]) @ Bt[256,K]^T + bias ----------------
// Persistent 512 blocks x 4 waves; block owns a 128-col half of B^T in LDS.
// A tiles double-buffered in registers: next tile's 8 indep loads issue right
// after current A is consumed, so HBM latency drains under MFMA+epilogue.
template <int K, bool TRANSFORM, bool RELU_OUT, bool COLSUMS>
__global__ __launch_bounds__(256)
void k_gemm(const u16* __restrict__ A, const u16* __restrict__ Bt,
            const float* __restrict__ bias, const float* __restrict__ ta,
            const float* __restrict__ tc, u16* __restrict__ C,
            float* __restrict__ csum, float* __restrict__ csq) {
  constexpr int NCH = K / 8;
  constexpr int NKS = K / 32;
  constexpr int NTILE = (NN + 31) / 32;
  __shared__ u16 Bs[128 * K];
  __shared__ u16 Cs[32 * CSTRIDE];
  __shared__ float2 Tb[K];

  const int tid = threadIdx.x;
  const int lane = tid & 63;
  const int w = tid >> 6;
  const int wm = w >> 1, wn = w & 1;
  const int lr = lane & 15, lq = lane >> 4;
  const int half = blockIdx.x & 1;
  const u16* Bth = Bt + (size_t)half * 128 * K;

  for (int i = tid; i < 128 * NCH; i += 256) {
    int row = i / NCH, c = i % NCH;
    short8 v = *(const short8*)&Bth[(size_t)row * K + c * 8];
    ((short8*)Bs)[row * NCH + (c ^ (row & 7))] = v;
  }
  if constexpr (TRANSFORM) {
    for (int k = tid; k < K; k += 256) Tb[k] = make_float2(ta[k], tc[k]);
  }

  float bv[4];
#pragma unroll
  for (int ni = 0; ni < 4; ++ni) bv[ni] = bias[half * 128 + wn * 64 + ni * 16 + lr];
  float colS[4] = {}, colQ[4] = {};

  __syncthreads();

  short8 bufA[NKS], bufB[NKS];

  auto LOADA = [&](short8* dst, int rt) {
    int row = rt * 32 + wm * 16 + lr;
    int rowc = row < NN ? row : NN - 1;
    const u16* Ap = &A[(size_t)rowc * K];
#pragma unroll
    for (int ks = 0; ks < NKS; ++ks)
      dst[ks] = *(const short8*)&Ap[ks * 32 + lq * 8];
  };

  auto BODY = [&](short8* cur, short8* nxt, int rt) {
    if constexpr (TRANSFORM) {
#pragma unroll
      for (int ks = 0; ks < NKS; ++ks) {
        short8 v = cur[ks];
#pragma unroll
        for (int j = 0; j < 8; ++j) {
          float2 tb = Tb[ks * 32 + lq * 8 + j];
          float f = __uint_as_float(((u32)(u16)v[j]) << 16);
          v[j] = (short)f2bf(fmaxf(fmaf(f, tb.x, tb.y), 0.f));
        }
        cur[ks] = v;
      }
    }
    if (rt + 256 < NTILE) LOADA(nxt, rt + 256);   // issue-early prefetch

    f32x4 acc[4];
#pragma unroll
    for (int ni = 0; ni < 4; ++ni) acc[ni] = (f32x4){0.f, 0.f, 0.f, 0.f};
    __builtin_amdgcn_s_setprio(1);
#pragma unroll
    for (int ks = 0; ks < NKS; ++ks) {
#pragma unroll
      for (int ni = 0; ni < 4; ++ni) {
        int col = wn * 64 + ni * 16 + lr;
        int c = (ks * 4 + lq) ^ (col & 7);
        short8 bfr = ((const short8*)Bs)[col * NCH + c];
        acc[ni] = __builtin_amdgcn_mfma_f32_16x16x32_bf16(cur[ks], bfr, acc[ni], 0, 0, 0);
      }
    }
    __builtin_amdgcn_s_setprio(0);

#pragma unroll
    for (int ni = 0; ni < 4; ++ni) {
      int col = wn * 64 + ni * 16 + lr;
#pragma unroll
      for (int j = 0; j < 4; ++j) {
        int r = wm * 16 + lq * 4 + j;
        float v = acc[ni][j] + bv[ni];
        if constexpr (RELU_OUT) v = fmaxf(v, 0.f);
        if constexpr (COLSUMS) {
          if (rt * 32 + r < NN) { colS[ni] += v; colQ[ni] += v * v; }
        }
        Cs[r * CSTRIDE + col] = f2bf(v);
      }
    }
    __syncthreads();
    {
      int r = tid >> 3;
      int gr = rt * 32 + r;
      if (gr < NN) {
        const uint4* src = (const uint4*)&Cs[r * CSTRIDE + (tid & 7) * 16];
        uint4 v0 = src[0], v1 = src[1];
        uint4* dst = (uint4*)&C[(size_t)gr * HDIM + half * 128 + (tid & 7) * 16];
        dst[0] = v0; dst[1] = v1;
      }
    }
    __syncthreads();
  };

  LOADA(bufA, blockIdx.x >> 1);
  for (int rt = blockIdx.x >> 1; rt < NTILE; rt += 512) {
    BODY(bufA, bufB, rt);
    if (rt + 256 < NTILE) BODY(bufB, bufA, rt + 256);
  }

  if constexpr (COLSUMS) {
#pragma unroll
    for (int ni = 0; ni < 4; ++ni) {
      float s = colS[ni], q = colQ[ni];
      s += __shfl_xor(s, 16); s += __shfl_xor(s, 32);
      q += __shfl_xor(q, 16); q += __shfl_xor(q, 32);
      if (lq == 0) {
        int col = half * 128 + wn * 64 + ni * 16 + lr;
        atomicAdd(&csum[col], s);
        atomicAdd(&csq[col], q);
      }
    }
  }
}

// ---------------- BN finalize ----------------
__global__ void k_bn_fin(const float* __restrict__ sum, const float* __restrict__ sq,
                         const float* __restrict__ g, const float* __restrict__ be,
                         float* __restrict__ a, float* __restrict__ c) {
  int t = threadIdx.x;
  float m = sum[t] * (1.0f / NN);
  float var = sq[t] * (1.0f / NN) - m * m;
  float s = g[t] * rsqrtf(var + BN_EPS);
  a[t] = s;
  c[t] = be[t] - m * s;
}

// ---------------- final GEMM: out[NN,40] = relu(z*ta+tc) @ Wf + bf (fp32 vector) ----------------
__global__ __launch_bounds__(256)
void k_gemm_final(const u16* __restrict__ A, const float* __restrict__ B,
                  const float* __restrict__ bias, const float* __restrict__ ta,
                  const float* __restrict__ tc, float* __restrict__ C) {
  __shared__ float As[64][65];
  __shared__ float Bs[64][CDIM];
  int tid = threadIdx.x;
  int r = tid & 63, q = tid >> 6;
  int r0 = blockIdx.x * 64;
  float acc[10] = {};
  for (int k0 = 0; k0 < HDIM; k0 += 64) {
#pragma unroll
    for (int i = 0; i < 4; ++i) {
      int idx = tid + i * 256;
      int row = idx >> 4;
      int c4 = (idx & 15) * 4;
      int gr = r0 + row;
      float v0 = 0.f, v1 = 0.f, v2 = 0.f, v3 = 0.f;
      if (gr < NN) {
        uint2 u = *(const uint2*)&A[(size_t)gr * HDIM + k0 + c4];
        v0 = fmaxf(fmaf(bflo(u.x), ta[k0 + c4 + 0], tc[k0 + c4 + 0]), 0.f);
        v1 = fmaxf(fmaf(bfhi(u.x), ta[k0 + c4 + 1], tc[k0 + c4 + 1]), 0.f);
        v2 = fmaxf(fmaf(bflo(u.y), ta[k0 + c4 + 2], tc[k0 + c4 + 2]), 0.f);
        v3 = fmaxf(fmaf(bfhi(u.y), ta[k0 + c4 + 3], tc[k0 + c4 + 3]), 0.f);
      }
      As[c4 + 0][row] = v0;
      As[c4 + 1][row] = v1;
      As[c4 + 2][row] = v2;
      As[c4 + 3][row] = v3;
    }
#pragma unroll
    for (int i = 0; i < 10; ++i) {
      int idx = tid + i * 256;
      int row = idx / CDIM;
      int col = idx % CDIM;
      Bs[row][col] = B[(size_t)(k0 + row) * CDIM + col];
    }
    __syncthreads();
#pragma unroll
    for (int k = 0; k < 64; ++k) {
      float a = As[k][r];
#pragma unroll
      for (int j = 0; j < 10; ++j) acc[j] = fmaf(a, Bs[k][q * 10 + j], acc[j]);
    }
    __syncthreads();
  }
  int gr = r0 + r;
  if (gr < NN) {
#pragma unroll
    for (int j = 0; j < 10; ++j) C[(size_t)gr * CDIM + q * 10 + j] = acc[j] + bias[q * 10 + j];
  }
}

// ---------------- launch ----------------
extern "C" void kernel_launch(void* const* d_in, const int* in_sizes, int n_in,
                              void* d_out, int out_size, void* d_ws, size_t ws_size,
                              hipStream_t stream) {
  const float* x   = (const float*)d_in[0];
  const int*   ei  = (const int*)d_in[1];
  const float* eps1= (const float*)d_in[2];
  const float* W1  = (const float*)d_in[3];
  const float* b1  = (const float*)d_in[4];
  const float* g1  = (const float*)d_in[5];
  const float* be1 = (const float*)d_in[6];
  const float* W2  = (const float*)d_in[7];
  const float* b2  = (const float*)d_in[8];
  const float* eps2= (const float*)d_in[9];
  const float* W3  = (const float*)d_in[10];
  const float* b3  = (const float*)d_in[11];
  const float* g2  = (const float*)d_in[12];
  const float* be2 = (const float*)d_in[13];
  const float* W4  = (const float*)d_in[14];
  const float* b4  = (const float*)d_in[15];
  const float* g3  = (const float*)d_in[16];
  const float* be3 = (const float*)d_in[17];
  const float* Wf  = (const float*)d_in[18];
  const float* bf  = (const float*)d_in[19];
  float* out = (float*)d_out;

  char* p = (char*)d_ws;
  auto alloc = [&](size_t bytes) -> char* {
    char* r = p;
    p += (bytes + 255) & ~(size_t)255;
    return r;
  };
  float* stats   = (float*)alloc(12 * 256 * sizeof(float));
  int* deg       = (int*)alloc(NN * sizeof(int));
  int* rowstart  = (int*)alloc((NN + 16) * sizeof(int));
  int* cursor    = (int*)alloc(NN * sizeof(int));
  int* sorted    = (int*)alloc(EE * sizeof(int));
  int* partial   = (int*)alloc(NN * sizeof(int));
  int* bsums     = (int*)alloc(1024 * sizeof(int));
  u16* W1t       = (u16*)alloc(256 * 128 * sizeof(u16));
  u16* W2t       = (u16*)alloc(256 * 256 * sizeof(u16));
  u16* W3t       = (u16*)alloc(256 * 256 * sizeof(u16));
  u16* W4t       = (u16*)alloc(256 * 256 * sizeof(u16));
  u16* xb        = (u16*)alloc((size_t)NN * 128 * sizeof(u16));
  u16* A1        = (u16*)alloc((size_t)NN * 128 * sizeof(u16));
  u16* z1        = (u16*)alloc((size_t)NN * 256 * sizeof(u16));
  u16* h1        = (u16*)alloc((size_t)NN * 256 * sizeof(u16));
  u16* A2        = (u16*)alloc((size_t)NN * 256 * sizeof(u16));
  (void)alloc(64 * 1024);  // guard pad
  u16* z2 = z1;
  u16* z3 = h1;

  hipMemsetAsync(deg, 0, NN * sizeof(int), stream);
  hipMemsetAsync(stats, 0, 12 * 256 * sizeof(float), stream);

  const int nbE = (EE + 255) / 256;
  const int nbN = (NN + 255) / 256;

  k_hist<<<nbE, 256, 0, stream>>>(ei, deg);
  k_scan_blocks<<<nbN, 256, 0, stream>>>(deg, partial, bsums, NN);
  k_scan_sums<<<1, 256, 0, stream>>>(bsums, nbN);
  k_scan_add<<<nbN, 256, 0, stream>>>(partial, bsums, rowstart, NN);
  k_copy_i32<<<nbN, 256, 0, stream>>>(rowstart, cursor, NN);
  k_scatter<<<nbE, 256, 0, stream>>>(ei, cursor, sorted);

  k_cvt_x<<<(NN * FDIM / 4 + 255) / 256, 256, 0, stream>>>(x, xb);
  k_cvt_wt<<<128, 256, 0, stream>>>(W1, W1t, 128);
  k_cvt_wt<<<256, 256, 0, stream>>>(W2, W2t, 256);
  k_cvt_wt<<<256, 256, 0, stream>>>(W3, W3t, 256);
  k_cvt_wt<<<256, 256, 0, stream>>>(W4, W4t, 256);

  // conv1
  k_agg<128><<<(NN + 3) / 4, 256, 0, stream>>>(xb, rowstart, sorted, eps1, A1);
  k_gemm<128, false, false, true><<<512, 256, 0, stream>>>(
      A1, W1t, b1, nullptr, nullptr, z1, stats + 0, stats + 256);
  k_bn_fin<<<1, 256, 0, stream>>>(stats + 0, stats + 256, g1, be1,
                                  stats + 2 * 256, stats + 3 * 256);
  k_gemm<256, true, true, false><<<512, 256, 0, stream>>>(
      z1, W2t, b2, stats + 2 * 256, stats + 3 * 256, h1, nullptr, nullptr);

  // conv2
  k_agg<256><<<(NN + 3) / 4, 256, 0, stream>>>(h1, rowstart, sorted, eps2, A2);
  k_gemm<256, false, false, true><<<512, 256, 0, stream>>>(
      A2, W3t, b3, nullptr, nullptr, z2, stats + 4 * 256, stats + 5 * 256);
  k_bn_fin<<<1, 256, 0, stream>>>(stats + 4 * 256, stats + 5 * 256, g2, be2,
                                  stats + 6 * 256, stats + 7 * 256);
  k_gemm<256, true, false, true><<<512, 256, 0, stream>>>(
      z2, W4t, b4, stats + 6 * 256, stats + 7 * 256, z3, stats + 8 * 256, stats + 9 * 256);
  k_bn_fin<<<1, 256, 0, stream>>>(stats + 8 * 256, stats + 9 * 256, g3, be3,
                                  stats + 10 * 256, stats + 11 * 256);

  k_gemm_final<<<(NN + 63) / 64, 256, 0, stream>>>(
      z3, Wf, bf, stats + 10 * 256, stats + 11 * 256, out);
}

// Round 6
// 378.349 us; speedup vs baseline: 1.9958x; 1.0345x over previous
//
#include <hip/hip_runtime.h>
#include <hip/hip_bf16.h>

// GIN forward, MI355X. Fused gather+GEMM conv kernels (B panel LDS-resident),
// BN folded into consumer preambles, MFMA final layer. 15 dispatches.

#define NN 50000
#define EE 800000
#define FDIM 128
#define HDIM 256
#define CDIM 40
#define BN_EPS 1e-5f
#define CSTRIDE 136   // k_gemm Cs row stride in u16

typedef unsigned short u16;
typedef unsigned int u32;
typedef __attribute__((ext_vector_type(8))) short short8;
typedef __attribute__((ext_vector_type(4))) float f32x4;

__device__ __forceinline__ float bflo(u32 u) { return __uint_as_float(u << 16); }
__device__ __forceinline__ float bfhi(u32 u) { return __uint_as_float(u & 0xFFFF0000u); }
__device__ __forceinline__ u16 f2bf(float f) {
  __hip_bfloat16 h = __float2bfloat16(f);
  return *(u16*)&h;
}
__device__ __forceinline__ u32 pack2(float a, float b) {
  return (u32)f2bf(a) | ((u32)f2bf(b) << 16);
}

// ---------------- CSR build ----------------
__global__ void k_hist(const int* __restrict__ ei, int* __restrict__ deg) {
  int e = blockIdx.x * 256 + threadIdx.x;
  if (e < EE) atomicAdd(&deg[ei[EE + e]], 1);
}

__global__ void k_scan_blocks(const int* __restrict__ in, int* __restrict__ partial,
                              int* __restrict__ bsums, int n) {
  __shared__ int s[256];
  int i = blockIdx.x * 256 + threadIdx.x;
  s[threadIdx.x] = (i < n) ? in[i] : 0;
  __syncthreads();
  for (int d = 1; d < 256; d <<= 1) {
    int t = (threadIdx.x >= d) ? s[threadIdx.x - d] : 0;
    __syncthreads();
    s[threadIdx.x] += t;
    __syncthreads();
  }
  if (i < n) partial[i] = s[threadIdx.x];
  if (threadIdx.x == 255) bsums[blockIdx.x] = s[255];
}

__global__ void k_scan_sums(int* __restrict__ bs, int nb) {
  __shared__ int s[256];
  s[threadIdx.x] = (threadIdx.x < nb) ? bs[threadIdx.x] : 0;
  __syncthreads();
  for (int d = 1; d < 256; d <<= 1) {
    int t = (threadIdx.x >= d) ? s[threadIdx.x - d] : 0;
    __syncthreads();
    s[threadIdx.x] += t;
    __syncthreads();
  }
  int ex = (threadIdx.x == 0) ? 0 : s[threadIdx.x - 1];
  if (threadIdx.x < nb) bs[threadIdx.x] = ex;
}

__global__ void k_scan_add(const int* __restrict__ partial, const int* __restrict__ bs,
                           int* __restrict__ rowstart, int n) {
  int i = blockIdx.x * 256 + threadIdx.x;
  if (i < n) rowstart[i + 1] = partial[i] + bs[blockIdx.x];
  if (i == 0) rowstart[0] = 0;
}

__global__ void k_copy_i32(const int* __restrict__ a, int* __restrict__ b, int n) {
  int i = blockIdx.x * 256 + threadIdx.x;
  if (i < n) b[i] = a[i];
}

__global__ void k_scatter(const int* __restrict__ ei, int* __restrict__ cursor,
                          int* __restrict__ sorted_src) {
  int e = blockIdx.x * 256 + threadIdx.x;
  if (e < EE) {
    int dst = ei[EE + e];
    int p = atomicAdd(&cursor[dst], 1);
    sorted_src[p] = ei[e];
  }
}

// ---------------- conversions ----------------
__global__ void k_cvt_x(const float* __restrict__ x, u16* __restrict__ xb) {
  int i = blockIdx.x * 256 + threadIdx.x;
  size_t base = (size_t)i * 4;
  if (base < (size_t)NN * FDIM) {
    float4 v = *(const float4*)&x[base];
    *(uint2*)&xb[base] = make_uint2(pack2(v.x, v.y), pack2(v.z, v.w));
  }
}

// all weights in one kernel: W1..W4 transpose+cvt, Wf -> padded [48][256]
__global__ void k_cvt_w(const float* __restrict__ W1, const float* __restrict__ W2,
                        const float* __restrict__ W3, const float* __restrict__ W4,
                        const float* __restrict__ Wf,
                        u16* __restrict__ W1t, u16* __restrict__ W2t,
                        u16* __restrict__ W3t, u16* __restrict__ W4t,
                        u16* __restrict__ Wft) {
  int b = blockIdx.x, t = threadIdx.x;
  if (b < 128) {
    int i = b * 256 + t; int k = i >> 8, n = i & 255;
    W1t[(size_t)n * 128 + k] = f2bf(W1[i]);
  } else if (b < 384) {
    int i = (b - 128) * 256 + t; int k = i >> 8, n = i & 255;
    W2t[(size_t)n * 256 + k] = f2bf(W2[i]);
  } else if (b < 640) {
    int i = (b - 384) * 256 + t; int k = i >> 8, n = i & 255;
    W3t[(size_t)n * 256 + k] = f2bf(W3[i]);
  } else if (b < 896) {
    int i = (b - 640) * 256 + t; int k = i >> 8, n = i & 255;
    W4t[(size_t)n * 256 + k] = f2bf(W4[i]);
  } else {
    int i = (b - 896) * 256 + t;      // 0..12287
    int c = i >> 8, k = i & 255;      // c: 0..47
    Wft[(size_t)c * 256 + k] = (c < CDIM) ? f2bf(Wf[(size_t)k * CDIM + c]) : (u16)0;
  }
}

// ---------------- fused conv: C[N,256] = (agg(X)[N,K]) @ Bt[256,K]^T + bias ----------------
// 1024 threads (16 waves, rg 2 x cg 8), 1 block/CU, 256 blocks. B panel resident
// in LDS. Per 32-row dst tile: each wave gathers 2 rows (f32 accum, 8-deep MLP),
// bf16 into LDS A tile (chunk-XOR swizzled), MFMA 16x16x32, C staged -> 512B lines.
template <int K>
__global__ __launch_bounds__(1024)
void k_fused(const u16* __restrict__ X, const int* __restrict__ rowstart,
             const int* __restrict__ sorted_src, const float* __restrict__ epsp,
             const u16* __restrict__ Bt, const float* __restrict__ bias,
             u16* __restrict__ C, float* __restrict__ csum, float* __restrict__ csq) {
  constexpr int NCH = K / 8;
  constexpr bool DB = (K == 128);
  constexpr int NTILE = (NN + 31) / 32;
  __shared__ u16 Bs[256 * K];                 // 64KB / 128KB
  __shared__ u16 As[DB ? 2 : 1][32 * K];      // 2x8KB / 1x16KB
  __shared__ u16 Cs[DB ? 32 * 272 : 8];       // C staging (K=128 only)

  const int tid = threadIdx.x;
  const int lane = tid & 63;
  const int w = tid >> 6;           // 0..15
  const int rg = w >> 3, cg = w & 7;
  const int lr = lane & 15, lq = lane >> 4;

  for (int i = tid; i < 256 * NCH; i += 1024) {
    int row = i / NCH, c = i % NCH;
    ((short8*)Bs)[row * NCH + (c ^ (row & 7))] = ((const short8*)Bt)[i];
  }
  const float e1 = 1.0f + epsp[0];
  float bv[2];
#pragma unroll
  for (int ni = 0; ni < 2; ++ni) bv[ni] = bias[cg * 32 + ni * 16 + lr];
  float colS[2] = {}, colQ[2] = {};

  auto GATHER = [&](int grow, float* a) {
    a[0] = a[1] = 0.f;
    if constexpr (!DB) { a[2] = a[3] = 0.f; }
    if (grow >= NN) return;
    int s = rowstart[grow], t = rowstart[grow + 1];
    if constexpr (!DB) {
      const uint2* xp = (const uint2*)X;   // 64 uint2 per 512B row
      uint2 u = xp[(size_t)grow * 64 + lane];
      a[0] = bflo(u.x) * e1; a[1] = bfhi(u.x) * e1;
      a[2] = bflo(u.y) * e1; a[3] = bfhi(u.y) * e1;
      int p = s;
      for (; p + 7 < t; p += 8) {
        uint2 uu[8];
#pragma unroll
        for (int i = 0; i < 8; ++i) uu[i] = xp[(size_t)sorted_src[p + i] * 64 + lane];
#pragma unroll
        for (int i = 0; i < 8; ++i) {
          a[0] += bflo(uu[i].x); a[1] += bfhi(uu[i].x);
          a[2] += bflo(uu[i].y); a[3] += bfhi(uu[i].y);
        }
      }
      for (; p < t; ++p) {
        uint2 u0 = xp[(size_t)sorted_src[p] * 64 + lane];
        a[0] += bflo(u0.x); a[1] += bfhi(u0.x);
        a[2] += bflo(u0.y); a[3] += bfhi(u0.y);
      }
    } else {
      const u32* xp = (const u32*)X;       // 64 u32 per 256B row
      u32 u = xp[(size_t)grow * 64 + lane];
      a[0] = bflo(u) * e1; a[1] = bfhi(u) * e1;
      int p = s;
      for (; p + 7 < t; p += 8) {
        u32 uu[8];
#pragma unroll
        for (int i = 0; i < 8; ++i) uu[i] = xp[(size_t)sorted_src[p + i] * 64 + lane];
#pragma unroll
        for (int i = 0; i < 8; ++i) { a[0] += bflo(uu[i]); a[1] += bfhi(uu[i]); }
      }
      for (; p < t; ++p) {
        u32 u0 = xp[(size_t)sorted_src[p] * 64 + lane];
        a[0] += bflo(u0); a[1] += bfhi(u0);
      }
    }
  };

  auto GWRITE = [&](u16* Abuf, int lw, const float* a) {
    if constexpr (!DB) {
      int idx = lw * 256 + (((lane >> 1) ^ (lw & 7)) << 3) + (lane & 1) * 4;
      *(uint2*)&Abuf[idx] = make_uint2(pack2(a[0], a[1]), pack2(a[2], a[3]));
    } else {
      int idx = lw * 128 + (((lane >> 2) ^ (lw & 7)) << 3) + (lane & 3) * 2;
      *(u32*)&Abuf[idx] = pack2(a[0], a[1]);
    }
  };

  const int arow = rg * 16 + lr;
  auto MFMA_TILE = [&](const u16* Abuf, f32x4* acc) {
    acc[0] = (f32x4){0.f, 0.f, 0.f, 0.f};
    acc[1] = (f32x4){0.f, 0.f, 0.f, 0.f};
    __builtin_amdgcn_s_setprio(1);
#pragma unroll
    for (int ks = 0; ks < K / 32; ++ks) {
      short8 af = *(const short8*)&Abuf[arow * K + (((ks * 4 + lq) ^ (arow & 7)) << 3)];
#pragma unroll
      for (int ni = 0; ni < 2; ++ni) {
        int col = cg * 32 + ni * 16 + lr;
        short8 bfr = ((const short8*)Bs)[col * NCH + ((ks * 4 + lq) ^ (col & 7))];
        acc[ni] = __builtin_amdgcn_mfma_f32_16x16x32_bf16(af, bfr, acc[ni], 0, 0, 0);
      }
    }
    __builtin_amdgcn_s_setprio(0);
  };

  const int rt0 = blockIdx.x;
  float ga0[4], ga1[4];
  GATHER(rt0 * 32 + w * 2 + 0, ga0);
  GATHER(rt0 * 32 + w * 2 + 1, ga1);
  GWRITE(As[0], w * 2 + 0, ga0);
  GWRITE(As[0], w * 2 + 1, ga1);
  __syncthreads();

  int cur = 0;
  for (int rt = rt0; rt < NTILE; rt += 256) {
    f32x4 acc[2];
    MFMA_TILE(As[cur], acc);
    bool hn = (rt + 256) < NTILE;
    if (hn) {
      GATHER((rt + 256) * 32 + w * 2 + 0, ga0);
      GATHER((rt + 256) * 32 + w * 2 + 1, ga1);
    }
    if constexpr (DB) {
      // epilogue -> Cs; gathered next -> other A buffer
#pragma unroll
      for (int ni = 0; ni < 2; ++ni) {
        int col = cg * 32 + ni * 16 + lr;
#pragma unroll
        for (int j = 0; j < 4; ++j) {
          int r = rg * 16 + lq * 4 + j;
          float v = acc[ni][j] + bv[ni];
          if (rt * 32 + r < NN) { colS[ni] += v; colQ[ni] += v * v; }
          Cs[r * 272 + col] = f2bf(v);
        }
      }
      if (hn) {
        GWRITE(As[cur ^ 1], w * 2 + 0, ga0);
        GWRITE(As[cur ^ 1], w * 2 + 1, ga1);
      }
      __syncthreads();
      {
        int r = tid >> 5, ch = tid & 31;
        int gr = rt * 32 + r;
        if (gr < NN) {
          uint4 v = *(const uint4*)&Cs[r * 272 + ch * 8];
          *(uint4*)&C[(size_t)gr * 256 + ch * 8] = v;
        }
      }
      __syncthreads();
      cur ^= 1;
    } else {
      __syncthreads();   // all MFMA reads of As done
#pragma unroll
      for (int ni = 0; ni < 2; ++ni) {
        int col = cg * 32 + ni * 16 + lr;
#pragma unroll
        for (int j = 0; j < 4; ++j) {
          int r = rg * 16 + lq * 4 + j;
          float v = acc[ni][j] + bv[ni];
          if (rt * 32 + r < NN) { colS[ni] += v; colQ[ni] += v * v; }
          As[0][r * 256 + (((col >> 3) ^ (r & 7)) << 3) + (col & 7)] = f2bf(v);
        }
      }
      __syncthreads();
      {
        int r = tid >> 5, ch = tid & 31;
        int gr = rt * 32 + r;
        if (gr < NN) {
          uint4 v = *(const uint4*)&As[0][r * 256 + ((ch ^ (r & 7)) << 3)];
          *(uint4*)&C[(size_t)gr * 256 + ch * 8] = v;
        }
      }
      __syncthreads();
      if (hn) {
        GWRITE(As[0], w * 2 + 0, ga0);
        GWRITE(As[0], w * 2 + 1, ga1);
      }
      __syncthreads();
    }
  }

#pragma unroll
  for (int ni = 0; ni < 2; ++ni) {
    float s = colS[ni], q = colQ[ni];
    s += __shfl_xor(s, 16); s += __shfl_xor(s, 32);
    q += __shfl_xor(q, 16); q += __shfl_xor(q, 32);
    if (lq == 0) {
      int col = cg * 32 + ni * 16 + lr;
      atomicAdd(&csum[col], s);
      atomicAdd(&csq[col], q);
    }
  }
}

// ---------------- standalone GEMM (K=256): C = relu(bn(A)) @ Bt^T + bias ----------------
// BN scale/shift computed in-preamble from csum/csq/g/be. Persistent, half-col blocks.
template <bool RELU_OUT, bool COLSUMS>
__global__ __launch_bounds__(256)
void k_gemm(const u16* __restrict__ A, const u16* __restrict__ Bt,
            const float* __restrict__ bias,
            const float* __restrict__ icsum, const float* __restrict__ icsq,
            const float* __restrict__ g, const float* __restrict__ be,
            u16* __restrict__ C, float* __restrict__ ocsum, float* __restrict__ ocsq) {
  constexpr int K = 256;
  constexpr int NCH = K / 8;
  constexpr int NKS = K / 32;
  constexpr int NTILE = (NN + 31) / 32;
  __shared__ u16 Bs[128 * K];
  __shared__ u16 Cs[32 * CSTRIDE];
  __shared__ float2 Tb[K];

  const int tid = threadIdx.x;
  const int lane = tid & 63;
  const int w = tid >> 6;
  const int wm = w >> 1, wn = w & 1;
  const int lr = lane & 15, lq = lane >> 4;
  const int half = blockIdx.x & 1;
  const u16* Bth = Bt + (size_t)half * 128 * K;

  for (int i = tid; i < 128 * NCH; i += 256) {
    int row = i / NCH, c = i % NCH;
    short8 v = *(const short8*)&Bth[(size_t)row * K + c * 8];
    ((short8*)Bs)[row * NCH + (c ^ (row & 7))] = v;
  }
  if (tid < 256) {
    float m = icsum[tid] * (1.0f / NN);
    float var = icsq[tid] * (1.0f / NN) - m * m;
    float s = g[tid] * rsqrtf(var + BN_EPS);
    Tb[tid] = make_float2(s, be[tid] - m * s);
  }

  float bv[4];
#pragma unroll
  for (int ni = 0; ni < 4; ++ni) bv[ni] = bias[half * 128 + wn * 64 + ni * 16 + lr];
  float colS[4] = {}, colQ[4] = {};

  __syncthreads();

  short8 bufA[NKS], bufB[NKS];

  auto LOADA = [&](short8* dst, int rt) {
    int row = rt * 32 + wm * 16 + lr;
    int rowc = row < NN ? row : NN - 1;
    const u16* Ap = &A[(size_t)rowc * K];
#pragma unroll
    for (int ks = 0; ks < NKS; ++ks)
      dst[ks] = *(const short8*)&Ap[ks * 32 + lq * 8];
  };

  auto BODY = [&](short8* cur, short8* nxt, int rt) {
#pragma unroll
    for (int ks = 0; ks < NKS; ++ks) {
      short8 v = cur[ks];
#pragma unroll
      for (int j = 0; j < 8; ++j) {
        float2 tb = Tb[ks * 32 + lq * 8 + j];
        float f = __uint_as_float(((u32)(u16)v[j]) << 16);
        v[j] = (short)f2bf(fmaxf(fmaf(f, tb.x, tb.y), 0.f));
      }
      cur[ks] = v;
    }
    if (rt + 256 < NTILE) LOADA(nxt, rt + 256);

    f32x4 acc[4];
#pragma unroll
    for (int ni = 0; ni < 4; ++ni) acc[ni] = (f32x4){0.f, 0.f, 0.f, 0.f};
    __builtin_amdgcn_s_setprio(1);
#pragma unroll
    for (int ks = 0; ks < NKS; ++ks) {
#pragma unroll
      for (int ni = 0; ni < 4; ++ni) {
        int col = wn * 64 + ni * 16 + lr;
        int c = (ks * 4 + lq) ^ (col & 7);
        short8 bfr = ((const short8*)Bs)[col * NCH + c];
        acc[ni] = __builtin_amdgcn_mfma_f32_16x16x32_bf16(cur[ks], bfr, acc[ni], 0, 0, 0);
      }
    }
    __builtin_amdgcn_s_setprio(0);

#pragma unroll
    for (int ni = 0; ni < 4; ++ni) {
      int col = wn * 64 + ni * 16 + lr;
#pragma unroll
      for (int j = 0; j < 4; ++j) {
        int r = wm * 16 + lq * 4 + j;
        float v = acc[ni][j] + bv[ni];
        if constexpr (RELU_OUT) v = fmaxf(v, 0.f);
        if constexpr (COLSUMS) {
          if (rt * 32 + r < NN) { colS[ni] += v; colQ[ni] += v * v; }
        }
        Cs[r * CSTRIDE + col] = f2bf(v);
      }
    }
    __syncthreads();
    {
      int r = tid >> 3;
      int gr = rt * 32 + r;
      if (gr < NN) {
        const uint4* src = (const uint4*)&Cs[r * CSTRIDE + (tid & 7) * 16];
        uint4 v0 = src[0], v1 = src[1];
        uint4* dst = (uint4*)&C[(size_t)gr * HDIM + half * 128 + (tid & 7) * 16];
        dst[0] = v0; dst[1] = v1;
      }
    }
    __syncthreads();
  };

  LOADA(bufA, blockIdx.x >> 1);
  for (int rt = blockIdx.x >> 1; rt < NTILE; rt += 512) {
    BODY(bufA, bufB, rt);
    if (rt + 256 < NTILE) BODY(bufB, bufA, rt + 256);
  }

  if constexpr (COLSUMS) {
#pragma unroll
    for (int ni = 0; ni < 4; ++ni) {
      float s = colS[ni], q = colQ[ni];
      s += __shfl_xor(s, 16); s += __shfl_xor(s, 32);
      q += __shfl_xor(q, 16); q += __shfl_xor(q, 32);
      if (lq == 0) {
        int col = half * 128 + wn * 64 + ni * 16 + lr;
        atomicAdd(&ocsum[col], s);
        atomicAdd(&ocsq[col], q);
      }
    }
  }
}

// ---------------- final: out[N,40] = relu(bn(z3)) @ Wf + bf  (MFMA, 48-col pad) ----------------
__global__ __launch_bounds__(256)
void k_final(const u16* __restrict__ z3, const u16* __restrict__ Wft,
             const float* __restrict__ bf,
             const float* __restrict__ icsum, const float* __restrict__ icsq,
             const float* __restrict__ g, const float* __restrict__ be,
             float* __restrict__ out) {
  __shared__ u16 Bs[48 * 256];
  __shared__ float2 Tb[256];
  const int tid = threadIdx.x;
  const int lane = tid & 63;
  const int w = tid >> 6;
  const int lr = lane & 15, lq = lane >> 4;

  for (int i = tid; i < 48 * 32; i += 256) {
    int row = i >> 5, c = i & 31;
    ((short8*)Bs)[row * 32 + (c ^ (row & 7))] = ((const short8*)Wft)[i];
  }
  if (tid < 256) {
    float m = icsum[tid] * (1.0f / NN);
    float var = icsq[tid] * (1.0f / NN) - m * m;
    float s = g[tid] * rsqrtf(var + BN_EPS);
    Tb[tid] = make_float2(s, be[tid] - m * s);
  }
  __syncthreads();

  int row = blockIdx.x * 64 + w * 16 + lr;
  int rowc = row < NN ? row : NN - 1;
  const u16* Ap = &z3[(size_t)rowc * 256];
  short8 a[8];
#pragma unroll
  for (int ks = 0; ks < 8; ++ks) {
    short8 v = *(const short8*)&Ap[ks * 32 + lq * 8];
#pragma unroll
    for (int j = 0; j < 8; ++j) {
      float2 tb = Tb[ks * 32 + lq * 8 + j];
      float f = __uint_as_float(((u32)(u16)v[j]) << 16);
      v[j] = (short)f2bf(fmaxf(fmaf(f, tb.x, tb.y), 0.f));
    }
    a[ks] = v;
  }

  f32x4 acc[3];
#pragma unroll
  for (int ni = 0; ni < 3; ++ni) acc[ni] = (f32x4){0.f, 0.f, 0.f, 0.f};
#pragma unroll
  for (int ks = 0; ks < 8; ++ks) {
#pragma unroll
    for (int ni = 0; ni < 3; ++ni) {
      int col = ni * 16 + lr;
      short8 bfr = ((const short8*)Bs)[col * 32 + ((ks * 4 + lq) ^ (col & 7))];
      acc[ni] = __builtin_amdgcn_mfma_f32_16x16x32_bf16(a[ks], bfr, acc[ni], 0, 0, 0);
    }
  }

#pragma unroll
  for (int ni = 0; ni < 3; ++ni) {
    int col = ni * 16 + lr;
    if (col < CDIM) {
      float bfv = bf[col];
#pragma unroll
      for (int j = 0; j < 4; ++j) {
        int gr = blockIdx.x * 64 + w * 16 + lq * 4 + j;
        if (gr < NN) out[(size_t)gr * CDIM + col] = acc[ni][j] + bfv;
      }
    }
  }
}

// ---------------- launch ----------------
extern "C" void kernel_launch(void* const* d_in, const int* in_sizes, int n_in,
                              void* d_out, int out_size, void* d_ws, size_t ws_size,
                              hipStream_t stream) {
  const float* x   = (const float*)d_in[0];
  const int*   ei  = (const int*)d_in[1];
  const float* eps1= (const float*)d_in[2];
  const float* W1  = (const float*)d_in[3];
  const float* b1  = (const float*)d_in[4];
  const float* g1  = (const float*)d_in[5];
  const float* be1 = (const float*)d_in[6];
  const float* W2  = (const float*)d_in[7];
  const float* b2  = (const float*)d_in[8];
  const float* eps2= (const float*)d_in[9];
  const float* W3  = (const float*)d_in[10];
  const float* b3  = (const float*)d_in[11];
  const float* g2  = (const float*)d_in[12];
  const float* be2 = (const float*)d_in[13];
  const float* W4  = (const float*)d_in[14];
  const float* b4  = (const float*)d_in[15];
  const float* g3  = (const float*)d_in[16];
  const float* be3 = (const float*)d_in[17];
  const float* Wf  = (const float*)d_in[18];
  const float* bf  = (const float*)d_in[19];
  float* out = (float*)d_out;

  char* p = (char*)d_ws;
  auto alloc = [&](size_t bytes) -> char* {
    char* r = p;
    p += (bytes + 255) & ~(size_t)255;
    return r;
  };
  float* stats   = (float*)alloc(6 * 256 * sizeof(float));  // s1,q1,s2,q2,s3,q3
  int* deg       = (int*)alloc(NN * sizeof(int));
  int* rowstart  = (int*)alloc((NN + 16) * sizeof(int));
  int* cursor    = (int*)alloc(NN * sizeof(int));
  int* sorted    = (int*)alloc(EE * sizeof(int));
  int* partial   = (int*)alloc(NN * sizeof(int));
  int* bsums     = (int*)alloc(1024 * sizeof(int));
  u16* W1t       = (u16*)alloc(256 * 128 * sizeof(u16));
  u16* W2t       = (u16*)alloc(256 * 256 * sizeof(u16));
  u16* W3t       = (u16*)alloc(256 * 256 * sizeof(u16));
  u16* W4t       = (u16*)alloc(256 * 256 * sizeof(u16));
  u16* Wft       = (u16*)alloc(48 * 256 * sizeof(u16));
  u16* xb        = (u16*)alloc((size_t)NN * 128 * sizeof(u16));
  u16* z1        = (u16*)alloc((size_t)NN * 256 * sizeof(u16));
  u16* h1        = (u16*)alloc((size_t)NN * 256 * sizeof(u16));
  (void)alloc(64 * 1024);  // guard pad for clamped OOB-adjacent reads
  u16* z2 = z1;  // z1 dead after gemm2
  u16* z3 = h1;  // h1 dead after fused2

  float* s1 = stats + 0,    *q1 = stats + 256;
  float* s2 = stats + 512,  *q2 = stats + 768;
  float* s3 = stats + 1024, *q3 = stats + 1280;

  hipMemsetAsync(deg, 0, NN * sizeof(int), stream);
  hipMemsetAsync(stats, 0, 6 * 256 * sizeof(float), stream);

  const int nbE = (EE + 255) / 256;
  const int nbN = (NN + 255) / 256;

  k_hist<<<nbE, 256, 0, stream>>>(ei, deg);
  k_scan_blocks<<<nbN, 256, 0, stream>>>(deg, partial, bsums, NN);
  k_scan_sums<<<1, 256, 0, stream>>>(bsums, nbN);
  k_scan_add<<<nbN, 256, 0, stream>>>(partial, bsums, rowstart, NN);
  k_copy_i32<<<nbN, 256, 0, stream>>>(rowstart, cursor, NN);
  k_scatter<<<nbE, 256, 0, stream>>>(ei, cursor, sorted);

  k_cvt_x<<<(NN * FDIM / 4 + 255) / 256, 256, 0, stream>>>(x, xb);
  k_cvt_w<<<944, 256, 0, stream>>>(W1, W2, W3, W4, Wf, W1t, W2t, W3t, W4t, Wft);

  // conv1: z1 = agg(x) @ W1 + b1 (+stats1)
  k_fused<128><<<256, 1024, 0, stream>>>(xb, rowstart, sorted, eps1, W1t, b1, z1, s1, q1);
  // h1 = relu(bn1(z1) @ W2 + b2)
  k_gemm<true, false><<<512, 256, 0, stream>>>(z1, W2t, b2, s1, q1, g1, be1, h1, nullptr, nullptr);
  // conv2: z2 = agg(h1) @ W3 + b3 (+stats2)
  k_fused<256><<<256, 1024, 0, stream>>>(h1, rowstart, sorted, eps2, W3t, b3, z2, s2, q2);
  // z3 = bn2(z2) @ W4 + b4 (+stats3)
  k_gemm<false, true><<<512, 256, 0, stream>>>(z2, W4t, b4, s2, q2, g2, be2, z3, s3, q3);
  // out = relu(bn3(z3)) @ Wf + bf
  k_final<<<(NN + 63) / 64, 256, 0, stream>>>(z3, Wft, bf, s3, q3, g3, be3, out);
}